// Round 1
// baseline (603.234 us; speedup 1.0000x reference)
//
#include <hip/hip_runtime.h>
#include <stdint.h>

#define N_ 160
#define B_ 16
#define C_ 64
#define S_ 80
#define TWO_C 128
#define BNN (B_*N_*N_)     // 409600 rows
#define ROWS_BN (B_*N_)    // 2560

typedef unsigned short u16;
using frag_ab = __attribute__((ext_vector_type(8))) short;   // 8 bf16
using frag_cd = __attribute__((ext_vector_type(4))) float;   // 4 f32

__device__ __forceinline__ u16 f2bf(float f) {
    union { float f; uint32_t u; } v; v.f = f;
    uint32_t u = v.u;
    return (u16)((u + 0x7FFFu + ((u >> 16) & 1u)) >> 16);   // RNE
}
__device__ __forceinline__ float bf2f(u16 h) {
    union { uint32_t u; float f; } v; v.u = ((uint32_t)h) << 16;
    return v.f;
}
__device__ __forceinline__ float lrelu(float x) { return x >= 0.f ? x : 0.01f * x; }

// ---------------- weight prep: f32 -> bf16 ----------------
__global__ void k_prep(const float* __restrict__ w1, const float* __restrict__ w2,
                       u16* __restrict__ w1b, u16* __restrict__ w2b) {
    int i = blockIdx.x * 256 + threadIdx.x;
    if (i < TWO_C * C_) { w1b[i] = f2bf(w1[i]); w2b[i] = f2bf(w2[i]); }
}

// ---------------- stage 1: z1[r,o] = sum_c sim[r,c]*w1[o,c]  (K=64, O=128) ----
// block: one (b,i), 32 j's, all 128 o. 4 waves: (j-half, o-half) per wave,
// each wave 4 o-tiles of 16.
__global__ __launch_bounds__(256)
void k_stage1(const float* __restrict__ v, const u16* __restrict__ w1b,
              u16* __restrict__ z1b) {
    __shared__ u16 simT[32 * 64];
    const int bid = blockIdx.x;
    const int jt = bid % 5;          // 5 j-tiles of 32 (N=160)
    const int ri = bid / 5;          // = b*N + i
    const int j0 = jt * 32;
    const int t = threadIdx.x;
    const int bb = ri / N_;
    const float* __restrict__ vi = v + (size_t)ri * C_;
    const float* __restrict__ vrow = v + (size_t)bb * N_ * C_;

    // B fragments from global (w1b is [o][k], k-contiguous = B^T layout), L1-resident
    const int w = t >> 6, lane = t & 63;
    const int l15 = lane & 15, kgrp = lane >> 4, k0 = kgrp * 8;
    const int jt16 = w & 1;
    const int obase = (w >> 1) * 64;
    frag_ab bfrag[4][2];
    #pragma unroll
    for (int tt = 0; tt < 4; tt++) {
        int o = obase + tt * 16 + l15;
        #pragma unroll
        for (int kk = 0; kk < 2; kk++)
            bfrag[tt][kk] = *reinterpret_cast<const frag_ab*>(w1b + o * 64 + kk * 32 + k0);
    }

    // build sim tile [32][64] bf16, XOR-swizzled (row stride 128B -> G4 conflict fix)
    {
        const int j = t >> 3;             // 0..31
        const int c0 = (t & 7) * 8;       // 0..56
        float fi[8] __attribute__((aligned(16)));
        float fj[8] __attribute__((aligned(16)));
        *reinterpret_cast<float4*>(&fi[0]) = *reinterpret_cast<const float4*>(vi + c0);
        *reinterpret_cast<float4*>(&fi[4]) = *reinterpret_cast<const float4*>(vi + c0 + 4);
        const float* vj = vrow + (size_t)(j0 + j) * C_ + c0;
        *reinterpret_cast<float4*>(&fj[0]) = *reinterpret_cast<const float4*>(vj);
        *reinterpret_cast<float4*>(&fj[4]) = *reinterpret_cast<const float4*>(vj + 4);
        frag_ab pack;
        #pragma unroll
        for (int q = 0; q < 8; q++) {
            float d = fi[q] - fj[q];
            pack[q] = (short)f2bf(d * d);
        }
        int idx = (j * 64 + c0) ^ ((j & 7) << 3);
        *reinterpret_cast<frag_ab*>(&simT[idx]) = pack;
    }
    __syncthreads();

    frag_cd acc[4];
    #pragma unroll
    for (int tt = 0; tt < 4; tt++) acc[tt] = frag_cd{0.f, 0.f, 0.f, 0.f};

    #pragma unroll
    for (int kk = 0; kk < 2; kk++) {
        const int rj = jt16 * 16 + l15;
        const int idx = (rj * 64 + kk * 32 + k0) ^ ((rj & 7) << 3);
        frag_ab a = *reinterpret_cast<const frag_ab*>(&simT[idx]);
        #pragma unroll
        for (int tt = 0; tt < 4; tt++)
            acc[tt] = __builtin_amdgcn_mfma_f32_16x16x32_bf16(a, bfrag[tt][kk], acc[tt], 0, 0, 0);
    }

    // C/D layout: col = lane&15, row = (lane>>4)*4 + reg   [verified, learn_hip m89/m91]
    const size_t rowbase = (size_t)ri * N_ + j0;
    #pragma unroll
    for (int tt = 0; tt < 4; tt++) {
        const int o = obase + tt * 16 + l15;
        #pragma unroll
        for (int r = 0; r < 4; r++) {
            const int jrow = jt16 * 16 + kgrp * 4 + r;
            z1b[(rowbase + jrow) * TWO_C + o] = f2bf(acc[tt][r]);
        }
    }
}

// ---------------- per-channel stats (sum, sumsq) -> block partials -----------
template <int CH>
__global__ __launch_bounds__(256)
void k_stats(const u16* __restrict__ z, size_t total, float* __restrict__ partials) {
    const int t = threadIdx.x;
    const size_t stride = (size_t)gridDim.x * 256;
    float s = 0.f, ss = 0.f;
    for (size_t idx = (size_t)blockIdx.x * 256 + t; idx < total; idx += stride) {
        float f = bf2f(z[idx]);
        s += f; ss += f * f;
    }
    __shared__ float ls[256], lss[256];
    ls[t] = s; lss[t] = ss;
    __syncthreads();
    if (t < CH) {
        float rs = 0.f, rss = 0.f;
        #pragma unroll
        for (int q = t; q < 256; q += CH) { rs += ls[q]; rss += lss[q]; }
        partials[(size_t)blockIdx.x * (2 * CH) + t] = rs;
        partials[(size_t)blockIdx.x * (2 * CH) + CH + t] = rss;
    }
}

__global__ __launch_bounds__(256)
void k_reduce_stats(const float* __restrict__ partials, int nblocks, int twoCH,
                    float* __restrict__ stats) {
    const int c = blockIdx.x;
    const int t = threadIdx.x;
    float s = 0.f;
    for (int b = t; b < nblocks; b += 256) s += partials[(size_t)b * twoCH + c];
    __shared__ float ls[256];
    ls[t] = s; __syncthreads();
    for (int off = 128; off; off >>= 1) { if (t < off) ls[t] += ls[t + off]; __syncthreads(); }
    if (t == 0) stats[c] = ls[0];
}

// ---------------- stage 2: z2[r,p] = sum_o lrelu(bn(z1[r,o]))*w2[p,o]  (K=128, P=64)
__global__ __launch_bounds__(256)
void k_stage2(const u16* __restrict__ z1b, const float* __restrict__ stats1,
              const float* __restrict__ g1, const float* __restrict__ b1,
              const u16* __restrict__ w2b, u16* __restrict__ z2b) {
    __shared__ u16 h1T[64 * 128];
    __shared__ float cA[128], cB[128];
    const int t = threadIdx.x;
    const size_t r0 = (size_t)blockIdx.x * 64;

    if (t < 128) {
        const float inv = 1.f / (float)BNN;
        float mean = stats1[t] * inv;
        float var  = stats1[128 + t] * inv - mean * mean;
        float a = g1[t] * rsqrtf(var + 1e-5f);
        cA[t] = a;
        cB[t] = b1[t] - mean * a;
    }
    __syncthreads();

    #pragma unroll
    for (int p = 0; p < 4; p++) {
        const int chunk = t + p * 256;       // 1024 chunks of 8 bf16
        const int row = chunk >> 4;
        const int c0 = (chunk & 15) * 8;
        frag_ab vraw = *reinterpret_cast<const frag_ab*>(z1b + (r0 + row) * TWO_C + c0);
        frag_ab pack;
        #pragma unroll
        for (int q = 0; q < 8; q++) {
            float f = bf2f((u16)vraw[q]);
            pack[q] = (short)f2bf(lrelu(f * cA[c0 + q] + cB[c0 + q]));
        }
        int idx = (row * 128 + c0) ^ ((row & 7) << 3);
        *reinterpret_cast<frag_ab*>(&h1T[idx]) = pack;
    }
    __syncthreads();

    const int w = t >> 6, lane = t & 63;
    const int l15 = lane & 15, kgrp = lane >> 4, k0 = kgrp * 8;
    frag_cd acc[4];
    #pragma unroll
    for (int tt = 0; tt < 4; tt++) acc[tt] = frag_cd{0.f, 0.f, 0.f, 0.f};

    #pragma unroll
    for (int kk = 0; kk < 4; kk++) {
        const int rr = w * 16 + l15;
        const int idx = (rr * 128 + kk * 32 + k0) ^ ((rr & 7) << 3);
        frag_ab a = *reinterpret_cast<const frag_ab*>(&h1T[idx]);
        #pragma unroll
        for (int tt = 0; tt < 4; tt++) {
            frag_ab b = *reinterpret_cast<const frag_ab*>(w2b + (tt * 16 + l15) * 128 + kk * 32 + k0);
            acc[tt] = __builtin_amdgcn_mfma_f32_16x16x32_bf16(a, b, acc[tt], 0, 0, 0);
        }
    }

    #pragma unroll
    for (int tt = 0; tt < 4; tt++) {
        const int o = tt * 16 + l15;
        #pragma unroll
        for (int r = 0; r < 4; r++) {
            const size_t row = r0 + w * 16 + kgrp * 4 + r;
            z2b[row * C_ + o] = f2bf(acc[tt][r]);
        }
    }
}

// ---------------- stage 3: e[r] = sigmoid( sum_p lrelu(bn(z2[r,p]))*w3[p] + b3 )
__global__ __launch_bounds__(256)
void k_stage3(const u16* __restrict__ z2b, const float* __restrict__ stats2,
              const float* __restrict__ g2, const float* __restrict__ b2,
              const float* __restrict__ w3, const float* __restrict__ b3,
              float* __restrict__ e_out) {
    const int t = threadIdx.x;
    const int lane = t & 63;
    const size_t row = (size_t)blockIdx.x * 4 + (t >> 6);
    const float inv = 1.f / (float)BNN;
    float mean = stats2[lane] * inv;
    float var  = stats2[64 + lane] * inv - mean * mean;
    float a = g2[lane] * rsqrtf(var + 1e-5f);
    float bc = b2[lane] - mean * a;
    float f = bf2f(z2b[row * C_ + lane]);
    float v = lrelu(f * a + bc) * w3[lane];
    #pragma unroll
    for (int off = 32; off; off >>= 1) v += __shfl_xor(v, off, 64);
    if (lane == 0) e_out[row] = 1.f / (1.f + __expf(-(v + b3[0])));
}

// ---------------- edge renormalization chain --------------------------------
__device__ __forceinline__ float block_sum(float v, float* lds) {
    #pragma unroll
    for (int off = 32; off; off >>= 1) v += __shfl_xor(v, off, 64);
    __syncthreads();
    if ((threadIdx.x & 63) == 0) lds[threadIdx.x >> 6] = v;
    __syncthreads();
    return lds[0] + lds[1] + lds[2] + lds[3];
}

__global__ __launch_bounds__(256)
void k_edge(const float* __restrict__ e, const float* __restrict__ ep_in,
            float* __restrict__ pe_out) {
    __shared__ float lds[4];
    const int r = blockIdx.x;          // b*N + i
    const int t = threadIdx.x;
    const int iLoc = r % N_;
    const bool valid = t < N_;
    float epv = valid ? ep_in[(size_t)r * N_ + t] : 0.f;
    float epm = (t == iLoc) ? 0.f : epv;
    float rs = block_sum(epm, lds);
    float ev = valid ? e[(size_t)r * N_ + t] : 0.f;
    float x = ev * epm;
    float s = block_sum(fabsf(x), lds);
    x = x / fmaxf(s, 1e-12f) * rs;
    x += ((t == iLoc) ? 1.f : 0.f) + 1e-6f;
    float tot = block_sum(valid ? x : 0.f, lds);
    if (valid) pe_out[(size_t)r * N_ + t] = x / tot;
}

// ---------------- P2DAgg: dn = lrelu(concat(pe[:, :S], dn) @ W^T + b) --------
__global__ __launch_bounds__(256)
void k_p2d(const float* __restrict__ pe, const float* __restrict__ dn_in,
           const float* __restrict__ W, const float* __restrict__ bias,
           float* __restrict__ dn_out) {
    __shared__ float xl[2 * S_];
    const int r = blockIdx.x;
    const int t = threadIdx.x;
    if (t < S_)            xl[t] = pe[(size_t)r * N_ + t];
    else if (t < 2 * S_)   xl[t] = dn_in[(size_t)r * S_ + (t - S_)];
    __syncthreads();
    if (t < S_) {
        float acc = bias[t];
        const float* wr = W + (size_t)t * (2 * S_);
        #pragma unroll 4
        for (int k = 0; k < 2 * S_; k++) acc += xl[k] * wr[k];
        dn_out[(size_t)r * S_ + t] = lrelu(acc);
    }
}

// ---------------- launch -----------------------------------------------------
extern "C" void kernel_launch(void* const* d_in, const int* in_sizes, int n_in,
                              void* d_out, int out_size, void* d_ws, size_t ws_size,
                              hipStream_t stream) {
    const float* middle = (const float*)d_in[0];
    const float* point  = (const float*)d_in[1];
    const float* dnode  = (const float*)d_in[2];
    // d_in[3] = distribution_edge: unused by the reference forward
    const float* pedge  = (const float*)d_in[4];
    const float* w1 = (const float*)d_in[5];
    const float* g1 = (const float*)d_in[6];
    const float* b1 = (const float*)d_in[7];
    const float* w2 = (const float*)d_in[8];
    const float* g2 = (const float*)d_in[9];
    const float* b2 = (const float*)d_in[10];
    const float* w3 = (const float*)d_in[11];
    const float* b3 = (const float*)d_in[12];
    const float* p2dw = (const float*)d_in[13];
    const float* p2db = (const float*)d_in[14];

    float* out0 = (float*)d_out;             // dn after generation 0
    float* out1 = out0 + (size_t)ROWS_BN * S_; // dn after generation 1

    char* ws = (char*)d_ws;
    size_t off = 0;
    auto alloc = [&](size_t bytes) -> char* {
        char* p = ws + off;
        off += (bytes + 255) & ~(size_t)255;
        return p;
    };
    u16*   z1b      = (u16*)  alloc((size_t)BNN * TWO_C * 2);   // 104.9 MB
    u16*   z2b      = (u16*)  alloc((size_t)BNN * C_ * 2);      //  52.4 MB
    u16*   w1b      = (u16*)  alloc(TWO_C * C_ * 2);
    u16*   w2b      = (u16*)  alloc(C_ * TWO_C * 2);
    float* e_buf    = (float*)alloc((size_t)BNN * 4);
    float* pe_a     = (float*)alloc((size_t)BNN * 4);
    float* pe_b     = (float*)alloc((size_t)BNN * 4);
    float* partials = (float*)alloc((size_t)1024 * 256 * 4);
    float* stats1   = (float*)alloc(256 * 4);
    float* stats2   = (float*)alloc(128 * 4);

    k_prep<<<32, 256, 0, stream>>>(w1, w2, w1b, w2b);

    // Two edge-score passes: call 0 -> middle_node, call 1 -> point_node.
    // e from point_node is reused for BOTH generations (it only depends on v).
    for (int call = 0; call < 2; call++) {
        const float* v = (call == 0) ? middle : point;
        k_stage1<<<ROWS_BN * 5, 256, 0, stream>>>(v, w1b, z1b);
        k_stats<128><<<1024, 256, 0, stream>>>(z1b, (size_t)BNN * TWO_C, partials);
        k_reduce_stats<<<256, 256, 0, stream>>>(partials, 1024, 256, stats1);
        k_stage2<<<BNN / 64, 256, 0, stream>>>(z1b, stats1, g1, b1, w2b, z2b);
        k_stats<64><<<1024, 256, 0, stream>>>(z2b, (size_t)BNN * C_, partials);
        k_reduce_stats<<<128, 256, 0, stream>>>(partials, 1024, 128, stats2);
        k_stage3<<<BNN / 4, 256, 0, stream>>>(z2b, stats2, g2, b2, w3, b3, e_buf);
        if (call == 0)
            k_edge<<<ROWS_BN, 256, 0, stream>>>(e_buf, pedge, pe_a);   // initial_edge
    }

    // generation 0
    k_edge<<<ROWS_BN, 256, 0, stream>>>(e_buf, pe_a, pe_b);            // pe1
    k_p2d<<<ROWS_BN, 256, 0, stream>>>(pe_b, dnode, p2dw, p2db, out0); // dn1
    // generation 1
    k_edge<<<ROWS_BN, 256, 0, stream>>>(e_buf, pe_b, pe_a);            // pe2
    k_p2d<<<ROWS_BN, 256, 0, stream>>>(pe_a, out0, p2dw + (size_t)S_ * 2 * S_,
                                       p2db + S_, out1);               // dn2
}

// Round 2
// 417.114 us; speedup vs baseline: 1.4462x; 1.4462x over previous
//
#include <hip/hip_runtime.h>
#include <stdint.h>

#define N_ 160
#define B_ 16
#define C_ 64
#define S_ 80
#define TWO_C 128
#define BNN (B_*N_*N_)     // 409600 rows
#define ROWS_BN (B_*N_)    // 2560

typedef unsigned short u16;
using frag_ab = __attribute__((ext_vector_type(8))) short;   // 8 bf16
using frag_cd = __attribute__((ext_vector_type(4))) float;   // 4 f32

__device__ __forceinline__ u16 f2bf(float f) {
    union { float f; uint32_t u; } v; v.f = f;
    uint32_t u = v.u;
    return (u16)((u + 0x7FFFu + ((u >> 16) & 1u)) >> 16);   // RNE
}
__device__ __forceinline__ float bf2f(u16 h) {
    union { uint32_t u; float f; } v; v.u = ((uint32_t)h) << 16;
    return v.f;
}
__device__ __forceinline__ float lrelu(float x) { return x >= 0.f ? x : 0.01f * x; }

// ---------------- weight prep: f32 -> bf16 ----------------
__global__ void k_prep(const float* __restrict__ w1, const float* __restrict__ w2,
                       u16* __restrict__ w1b, u16* __restrict__ w2b) {
    int i = blockIdx.x * 256 + threadIdx.x;
    if (i < TWO_C * C_) { w1b[i] = f2bf(w1[i]); w2b[i] = f2bf(w2[i]); }
}

// ---------------- closed-form BN1 stats: moments of v ------------------------
// grid 320 = b(16) x c1g(4) x ichunk(5); partial moments M2/M21/M22 per chunk.
__global__ __launch_bounds__(256)
void k_mom(const float* __restrict__ v, float* __restrict__ mom) {
    __shared__ __align__(16) float vl[32][64];
    const int bid = blockIdx.x;
    const int ic  = bid % 5;
    const int c1g = (bid / 5) % 4;
    const int b   = bid / 20;
    const int t = threadIdx.x;
    const float* src = v + ((size_t)b * N_ + ic * 32) * C_;
    #pragma unroll
    for (int p = 0; p < 2; p++) {
        int idx = t + p * 256;                 // float4 index (512 total)
        *reinterpret_cast<float4*>(&vl[0][0] + (size_t)idx * 4) =
            *reinterpret_cast<const float4*>(src + (size_t)idx * 4);
    }
    __syncthreads();
    const int c1 = c1g * 16 + (t >> 4);
    const int c2b = (t & 15) * 4;
    float m2[4] = {0,0,0,0}, m21[4] = {0,0,0,0}, m22[4] = {0,0,0,0};
    for (int i = 0; i < 32; i++) {
        float x1 = vl[i][c1];
        #pragma unroll
        for (int q = 0; q < 4; q++) {
            float x2 = vl[i][c2b + q];
            float tt = x1 * x2;
            m2[q]  += tt;
            m21[q] += x1 * tt;        // x1^2 * x2
            m22[q] += tt * tt;        // x1^2 * x2^2
        }
    }
    const int pl = (t >> 4) * 64 + c2b;
    float* base = mom + (size_t)bid * 3072;
    *reinterpret_cast<float4*>(base + pl)        = *reinterpret_cast<float4*>(m2);
    *reinterpret_cast<float4*>(base + 1024 + pl) = *reinterpret_cast<float4*>(m21);
    *reinterpret_cast<float4*>(base + 2048 + pl) = *reinterpret_cast<float4*>(m22);
}

__global__ __launch_bounds__(64)
void k_s1s2(const float* __restrict__ v, float* __restrict__ s1b, float* __restrict__ s2b) {
    const int b = blockIdx.x, c = threadIdx.x;
    float s1 = 0.f, s2 = 0.f;
    for (int i = 0; i < N_; i++) {
        float x = v[((size_t)b * N_ + i) * C_ + c];
        s1 += x; s2 += x * x;
    }
    s1b[b * 64 + c] = s1; s2b[b * 64 + c] = s2;
}

// S[c1,c2] = sum_b sum_{i,j} (v_ic1-v_jc1)^2 (v_ic2-v_jc2)^2   (+ T1 for means)
__global__ __launch_bounds__(256)
void k_S(const float* __restrict__ mom, const float* __restrict__ s1b,
         const float* __restrict__ s2b, float* __restrict__ Ssum, float* __restrict__ T1) {
    const int pi = blockIdx.x * 256 + threadIdx.x;   // 0..4095
    const int c1 = pi >> 6, c2 = pi & 63;
    float S = 0.f;
    for (int b = 0; b < 16; b++) {
        float m2 = 0.f, m21 = 0.f, m22 = 0.f, m21T = 0.f;
        const int bidA = (b * 4 + (c1 >> 4)) * 5;
        const int plA  = (c1 & 15) * 64 + c2;
        const int bidB = (b * 4 + (c2 >> 4)) * 5;
        const int plB  = (c2 & 15) * 64 + c1;
        #pragma unroll
        for (int ic = 0; ic < 5; ic++) {
            const float* base = mom + (size_t)(bidA + ic) * 3072;
            m2   += base[plA];
            m21  += base[1024 + plA];
            m22  += base[2048 + plA];
            m21T += mom[(size_t)(bidB + ic) * 3072 + 1024 + plB];
        }
        float s1c1 = s1b[b*64+c1], s1c2 = s1b[b*64+c2];
        float s2c1 = s2b[b*64+c1], s2c2 = s2b[b*64+c2];
        S += 2.f*(float)N_*m22 + 2.f*s2c1*s2c2 + 4.f*m2*m2
           - 4.f*m21*s1c2 - 4.f*m21T*s1c1;
    }
    Ssum[pi] = S;
    if (pi < 64) {
        float acc = 0.f;
        for (int b = 0; b < 16; b++) {
            float s1 = s1b[b*64+pi], s2 = s2b[b*64+pi];
            acc += 2.f*(float)N_*s2 - 2.f*s1*s1;
        }
        T1[pi] = acc;
    }
}

// per-o BN1 constants: cA = g*rsqrt(var+eps), cB = b - mean*cA
__global__ __launch_bounds__(64)
void k_bn1const(const float* __restrict__ Ssum, const float* __restrict__ T1,
                const float* __restrict__ w1, const float* __restrict__ g1,
                const float* __restrict__ b1, float* __restrict__ c1c) {
    const int o = blockIdx.x;      // 0..127
    const int c1 = threadIdx.x;    // 0..63
    const float* wrow = w1 + (size_t)o * 64;
    float wc1 = wrow[c1];
    float acc = 0.f;
    for (int c2 = 0; c2 < 64; c2++)
        acc += wrow[c2] * Ssum[c1 * 64 + c2];
    float qf = wc1 * acc;
    float mn = wc1 * T1[c1];
    #pragma unroll
    for (int off = 32; off; off >>= 1) {
        qf += __shfl_xor(qf, off, 64);
        mn += __shfl_xor(mn, off, 64);
    }
    if (c1 == 0) {
        const float inv = 1.f / (float)BNN;
        float mean = mn * inv;
        float var  = qf * inv - mean * mean;
        float a = g1[o] * rsqrtf(var + 1e-5f);
        c1c[o] = a;
        c1c[128 + o] = b1[o] - mean * a;
    }
}

// ---------------- fused: sim -> GEMM1 -> BN1+lrelu -> GEMM2 -> z2 + stats2 ---
__global__ __launch_bounds__(256)
void k_fused(const float* __restrict__ v, const u16* __restrict__ w1b,
             const float* __restrict__ c1c, const u16* __restrict__ w2b,
             u16* __restrict__ z2b, float* __restrict__ partials) {
    __shared__ __align__(16) u16 simT[32 * 64];
    __shared__ __align__(16) u16 h1T[32 * 128];
    __shared__ float sb_s[4][64];
    __shared__ float sb_ss[4][64];
    const int bid = blockIdx.x;
    const int jt = bid % 5;          // 5 j-tiles of 32
    const int ri = bid / 5;          // b*N + i
    const int j0 = jt * 32;
    const int t = threadIdx.x;
    const int bb = ri / N_;
    const int w = t >> 6, lane = t & 63;
    const int l15 = lane & 15, kgrp = lane >> 4, k0 = kgrp * 8;

    // ---- build sim tile [32][64] bf16, XOR-swizzled (validated pattern) ----
    {
        const float* __restrict__ vi = v + (size_t)ri * C_;
        const float* __restrict__ vrow = v + (size_t)bb * N_ * C_;
        const int j = t >> 3, c0 = (t & 7) * 8;
        float fi[8] __attribute__((aligned(16)));
        float fj[8] __attribute__((aligned(16)));
        *reinterpret_cast<float4*>(&fi[0]) = *reinterpret_cast<const float4*>(vi + c0);
        *reinterpret_cast<float4*>(&fi[4]) = *reinterpret_cast<const float4*>(vi + c0 + 4);
        const float* vj = vrow + (size_t)(j0 + j) * C_ + c0;
        *reinterpret_cast<float4*>(&fj[0]) = *reinterpret_cast<const float4*>(vj);
        *reinterpret_cast<float4*>(&fj[4]) = *reinterpret_cast<const float4*>(vj + 4);
        frag_ab pack;
        #pragma unroll
        for (int q = 0; q < 8; q++) {
            float d = fi[q] - fj[q];
            pack[q] = (short)f2bf(d * d);
        }
        int idx = (j * 64 + c0) ^ ((j & 7) << 3);
        *reinterpret_cast<frag_ab*>(&simT[idx]) = pack;
    }

    // ---- GEMM1 B fragments (w1b [o=128][k=64], L1-resident) ----
    const int jt16 = w & 1;
    const int obase = (w >> 1) * 64;
    frag_ab bfrag[4][2];
    #pragma unroll
    for (int tt = 0; tt < 4; tt++) {
        int o = obase + tt * 16 + l15;
        #pragma unroll
        for (int kk = 0; kk < 2; kk++)
            bfrag[tt][kk] = *reinterpret_cast<const frag_ab*>(w1b + o * 64 + kk * 32 + k0);
    }
    __syncthreads();

    // ---- GEMM1 ----
    frag_cd acc1[4];
    #pragma unroll
    for (int tt = 0; tt < 4; tt++) acc1[tt] = frag_cd{0.f, 0.f, 0.f, 0.f};
    #pragma unroll
    for (int kk = 0; kk < 2; kk++) {
        const int rj = jt16 * 16 + l15;
        const int idx = (rj * 64 + kk * 32 + k0) ^ ((rj & 7) << 3);
        frag_ab a = *reinterpret_cast<const frag_ab*>(&simT[idx]);
        #pragma unroll
        for (int tt = 0; tt < 4; tt++)
            acc1[tt] = __builtin_amdgcn_mfma_f32_16x16x32_bf16(a, bfrag[tt][kk], acc1[tt], 0, 0, 0);
    }

    // ---- BN1 + lrelu -> h1T [32][128] bf16, swizzled ----
    // C/D layout: col = lane&15, row = (lane>>4)*4 + reg
    #pragma unroll
    for (int tt = 0; tt < 4; tt++) {
        const int o = obase + tt * 16 + l15;
        const float a = c1c[o], bcon = c1c[128 + o];
        #pragma unroll
        for (int r = 0; r < 4; r++) {
            const int row = jt16 * 16 + kgrp * 4 + r;
            float hv = lrelu(acc1[tt][r] * a + bcon);
            h1T[(row * 128 + o) ^ ((row & 7) << 3)] = f2bf(hv);
        }
    }
    __syncthreads();

    // ---- GEMM2: rows re-split by rh = w>>1, cols by q = w&1 ----
    const int rh = w >> 1, q = w & 1;
    frag_cd acc2[2];
    acc2[0] = frag_cd{0.f,0.f,0.f,0.f}; acc2[1] = frag_cd{0.f,0.f,0.f,0.f};
    #pragma unroll
    for (int kk = 0; kk < 4; kk++) {
        const int rr = rh * 16 + l15;
        const int idx = (rr * 128 + kk * 32 + k0) ^ ((rr & 7) << 3);
        frag_ab a = *reinterpret_cast<const frag_ab*>(&h1T[idx]);
        #pragma unroll
        for (int tt = 0; tt < 2; tt++) {
            const int p = q * 32 + tt * 16 + l15;
            frag_ab bfr = *reinterpret_cast<const frag_ab*>(w2b + (size_t)p * 128 + kk * 32 + k0);
            acc2[tt] = __builtin_amdgcn_mfma_f32_16x16x32_bf16(a, bfr, acc2[tt], 0, 0, 0);
        }
    }

    // ---- z2 store + per-channel stats ----
    const size_t rowbase = (size_t)ri * N_ + j0;
    float s_l[2] = {0.f, 0.f}, ss_l[2] = {0.f, 0.f};
    #pragma unroll
    for (int tt = 0; tt < 2; tt++) {
        const int p = q * 32 + tt * 16 + l15;
        #pragma unroll
        for (int r = 0; r < 4; r++) {
            const int row = rh * 16 + kgrp * 4 + r;
            float val = acc2[tt][r];
            z2b[(rowbase + row) * C_ + p] = f2bf(val);
            s_l[tt] += val; ss_l[tt] += val * val;
        }
    }
    #pragma unroll
    for (int tt = 0; tt < 2; tt++) {
        s_l[tt]  += __shfl_xor(s_l[tt], 16, 64);  s_l[tt]  += __shfl_xor(s_l[tt], 32, 64);
        ss_l[tt] += __shfl_xor(ss_l[tt], 16, 64); ss_l[tt] += __shfl_xor(ss_l[tt], 32, 64);
    }
    if (lane < 16) {
        #pragma unroll
        for (int tt = 0; tt < 2; tt++) {
            const int p = q * 32 + tt * 16 + l15;
            sb_s[w][p]  = s_l[tt];
            sb_ss[w][p] = ss_l[tt];
        }
    }
    __syncthreads();
    if (t < 64) {
        const int qq = t >> 5;
        partials[(size_t)bid * 128 + t]      = sb_s[qq][t]  + sb_s[qq + 2][t];
        partials[(size_t)bid * 128 + 64 + t] = sb_ss[qq][t] + sb_ss[qq + 2][t];
    }
}

__global__ __launch_bounds__(256)
void k_reduce_stats(const float* __restrict__ partials, int nblocks, int twoCH,
                    float* __restrict__ stats) {
    const int c = blockIdx.x;
    const int t = threadIdx.x;
    float s = 0.f;
    for (int b = t; b < nblocks; b += 256) s += partials[(size_t)b * twoCH + c];
    __shared__ float ls[256];
    ls[t] = s; __syncthreads();
    for (int off = 128; off; off >>= 1) { if (t < off) ls[t] += ls[t + off]; __syncthreads(); }
    if (t == 0) stats[c] = ls[0];
}

__global__ __launch_bounds__(64)
void k_bn2const(const float* __restrict__ stats2, const float* __restrict__ g2,
                const float* __restrict__ b2, float* __restrict__ c2c) {
    const int c = threadIdx.x;  // 0..63
    const float inv = 1.f / (float)BNN;
    float mean = stats2[c] * inv;
    float var  = stats2[64 + c] * inv - mean * mean;
    float a = g2[c] * rsqrtf(var + 1e-5f);
    c2c[c] = a; c2c[64 + c] = b2[c] - mean * a;
}

// ---------------- e = sigmoid( sum_p lrelu(bn2(z2)) * w3 + b3 ) --------------
__global__ __launch_bounds__(256)
void k_escore(const u16* __restrict__ z2b, const float* __restrict__ c2c,
              const float* __restrict__ w3, const float* __restrict__ b3,
              float* __restrict__ e_out) {
    __shared__ float cs[192];
    const int t = threadIdx.x;
    if (t < 128) cs[t] = c2c[t];
    else if (t < 192) cs[t] = w3[t - 128];
    __syncthreads();
    const size_t row = (size_t)blockIdx.x * 32 + (t >> 3);
    const int c0 = (t & 7) * 8;
    frag_ab z = *reinterpret_cast<const frag_ab*>(z2b + row * C_ + c0);
    float acc = 0.f;
    #pragma unroll
    for (int qi = 0; qi < 8; qi++) {
        const int c = c0 + qi;
        float f = bf2f((u16)z[qi]);
        acc += lrelu(f * cs[c] + cs[64 + c]) * cs[128 + c];
    }
    acc += __shfl_xor(acc, 1, 64); acc += __shfl_xor(acc, 2, 64); acc += __shfl_xor(acc, 4, 64);
    if ((t & 7) == 0) e_out[row] = 1.f / (1.f + __expf(-(acc + b3[0])));
}

// ---------------- edge renormalization chain --------------------------------
__device__ __forceinline__ float block_sum(float v, float* lds) {
    #pragma unroll
    for (int off = 32; off; off >>= 1) v += __shfl_xor(v, off, 64);
    __syncthreads();
    if ((threadIdx.x & 63) == 0) lds[threadIdx.x >> 6] = v;
    __syncthreads();
    return lds[0] + lds[1] + lds[2] + lds[3];
}

__global__ __launch_bounds__(256)
void k_edge(const float* __restrict__ e, const float* __restrict__ ep_in,
            float* __restrict__ pe_out) {
    __shared__ float lds[4];
    const int r = blockIdx.x;          // b*N + i
    const int t = threadIdx.x;
    const int iLoc = r % N_;
    const bool valid = t < N_;
    float epv = valid ? ep_in[(size_t)r * N_ + t] : 0.f;
    float epm = (t == iLoc) ? 0.f : epv;
    float rs = block_sum(epm, lds);
    float ev = valid ? e[(size_t)r * N_ + t] : 0.f;
    float x = ev * epm;
    float s = block_sum(fabsf(x), lds);
    x = x / fmaxf(s, 1e-12f) * rs;
    x += ((t == iLoc) ? 1.f : 0.f) + 1e-6f;
    float tot = block_sum(valid ? x : 0.f, lds);
    if (valid) pe_out[(size_t)r * N_ + t] = x / tot;
}

// ---------------- P2DAgg ----------------------------------------------------
__global__ __launch_bounds__(256)
void k_p2d(const float* __restrict__ pe, const float* __restrict__ dn_in,
           const float* __restrict__ W, const float* __restrict__ bias,
           float* __restrict__ dn_out) {
    __shared__ float xl[2 * S_];
    const int r = blockIdx.x;
    const int t = threadIdx.x;
    if (t < S_)            xl[t] = pe[(size_t)r * N_ + t];
    else if (t < 2 * S_)   xl[t] = dn_in[(size_t)r * S_ + (t - S_)];
    __syncthreads();
    if (t < S_) {
        float acc = bias[t];
        const float* wr = W + (size_t)t * (2 * S_);
        #pragma unroll 4
        for (int k = 0; k < 2 * S_; k++) acc += xl[k] * wr[k];
        dn_out[(size_t)r * S_ + t] = lrelu(acc);
    }
}

// ---------------- launch -----------------------------------------------------
extern "C" void kernel_launch(void* const* d_in, const int* in_sizes, int n_in,
                              void* d_out, int out_size, void* d_ws, size_t ws_size,
                              hipStream_t stream) {
    const float* middle = (const float*)d_in[0];
    const float* point  = (const float*)d_in[1];
    const float* dnode  = (const float*)d_in[2];
    // d_in[3] = distribution_edge: unused by the reference forward
    const float* pedge  = (const float*)d_in[4];
    const float* w1 = (const float*)d_in[5];
    const float* g1 = (const float*)d_in[6];
    const float* b1 = (const float*)d_in[7];
    const float* w2 = (const float*)d_in[8];
    const float* g2 = (const float*)d_in[9];
    const float* b2 = (const float*)d_in[10];
    const float* w3 = (const float*)d_in[11];
    const float* b3 = (const float*)d_in[12];
    const float* p2dw = (const float*)d_in[13];
    const float* p2db = (const float*)d_in[14];

    float* out0 = (float*)d_out;
    float* out1 = out0 + (size_t)ROWS_BN * S_;

    char* ws = (char*)d_ws;
    size_t off = 0;
    auto alloc = [&](size_t bytes) -> char* {
        char* p = ws + off;
        off += (bytes + 255) & ~(size_t)255;
        return p;
    };
    u16*   z2b      = (u16*)  alloc((size_t)BNN * C_ * 2);      // 52.4 MB
    u16*   w1b      = (u16*)  alloc(TWO_C * C_ * 2);
    u16*   w2b      = (u16*)  alloc(C_ * TWO_C * 2);
    float* e_buf    = (float*)alloc((size_t)BNN * 4);
    float* pe_a     = (float*)alloc((size_t)BNN * 4);
    float* pe_b     = (float*)alloc((size_t)BNN * 4);
    float* partials = (float*)alloc((size_t)12800 * 128 * 4);   // 6.55 MB
    float* mom      = (float*)alloc((size_t)320 * 3072 * 4);    // 3.93 MB
    float* s1b      = (float*)alloc(16 * 64 * 4);
    float* s2b      = (float*)alloc(16 * 64 * 4);
    float* Ssum     = (float*)alloc(4096 * 4);
    float* T1       = (float*)alloc(64 * 4);
    float* c1c      = (float*)alloc(256 * 4);
    float* stats2   = (float*)alloc(128 * 4);
    float* c2c      = (float*)alloc(128 * 4);

    k_prep<<<32, 256, 0, stream>>>(w1, w2, w1b, w2b);

    // Two edge-score passes: call 0 -> middle_node, call 1 -> point_node.
    // e from point_node is reused for BOTH generations (depends only on v).
    for (int call = 0; call < 2; call++) {
        const float* v = (call == 0) ? middle : point;
        k_mom<<<320, 256, 0, stream>>>(v, mom);
        k_s1s2<<<16, 64, 0, stream>>>(v, s1b, s2b);
        k_S<<<16, 256, 0, stream>>>(mom, s1b, s2b, Ssum, T1);
        k_bn1const<<<128, 64, 0, stream>>>(Ssum, T1, w1, g1, b1, c1c);
        k_fused<<<ROWS_BN * 5, 256, 0, stream>>>(v, w1b, c1c, w2b, z2b, partials);
        k_reduce_stats<<<128, 256, 0, stream>>>(partials, 12800, 128, stats2);
        k_bn2const<<<1, 64, 0, stream>>>(stats2, g2, b2, c2c);
        k_escore<<<BNN / 32, 256, 0, stream>>>(z2b, c2c, w3, b3, e_buf);
        if (call == 0)
            k_edge<<<ROWS_BN, 256, 0, stream>>>(e_buf, pedge, pe_a);   // initial_edge
    }

    // generation 0
    k_edge<<<ROWS_BN, 256, 0, stream>>>(e_buf, pe_a, pe_b);
    k_p2d<<<ROWS_BN, 256, 0, stream>>>(pe_b, dnode, p2dw, p2db, out0);
    // generation 1
    k_edge<<<ROWS_BN, 256, 0, stream>>>(e_buf, pe_b, pe_a);
    k_p2d<<<ROWS_BN, 256, 0, stream>>>(pe_a, out0, p2dw + (size_t)S_ * 2 * S_,
                                       p2db + S_, out1);
}

// Round 3
// 276.907 us; speedup vs baseline: 2.1785x; 1.5063x over previous
//
#include <hip/hip_runtime.h>
#include <stdint.h>

#define N_ 160
#define B_ 16
#define C_ 64
#define S_ 80
#define TWO_C 128
#define BNN (B_*N_*N_)     // 409600 rows
#define ROWS_BN (B_*N_)    // 2560

typedef unsigned short u16;
using frag_ab = __attribute__((ext_vector_type(8))) short;   // 8 bf16
using frag_cd = __attribute__((ext_vector_type(4))) float;   // 4 f32

__device__ __forceinline__ u16 f2bf(float f) {
    union { float f; uint32_t u; } v; v.f = f;
    uint32_t u = v.u;
    return (u16)((u + 0x7FFFu + ((u >> 16) & 1u)) >> 16);   // RNE
}
__device__ __forceinline__ float bf2f(u16 h) {
    union { uint32_t u; float f; } v; v.u = ((uint32_t)h) << 16;
    return v.f;
}
__device__ __forceinline__ float lrelu(float x) { return x >= 0.f ? x : 0.01f * x; }

// ---------------- weight prep: f32 -> bf16 ----------------
__global__ void k_prep(const float* __restrict__ w1, const float* __restrict__ w2,
                       u16* __restrict__ w1b, u16* __restrict__ w2b) {
    int i = blockIdx.x * 256 + threadIdx.x;
    if (i < TWO_C * C_) { w1b[i] = f2bf(w1[i]); w2b[i] = f2bf(w2[i]); }
}

// ---------------- closed-form BN1 stats: moments of v ------------------------
// grid 320 = b(16) x c1g(4) x ichunk(5); partial moments M2/M21/M22 per chunk.
// c1g==0 blocks additionally emit per-chunk s1/s2 partials (k_s1s2 folded in).
__global__ __launch_bounds__(256)
void k_mom(const float* __restrict__ v, float* __restrict__ mom,
           float* __restrict__ s1p, float* __restrict__ s2p) {
    __shared__ __align__(16) float vl[32][64];
    const int bid = blockIdx.x;
    const int ic  = bid % 5;
    const int c1g = (bid / 5) % 4;
    const int b   = bid / 20;
    const int t = threadIdx.x;
    const float* src = v + ((size_t)b * N_ + ic * 32) * C_;
    #pragma unroll
    for (int p = 0; p < 2; p++) {
        int idx = t + p * 256;                 // float4 index (512 total)
        *reinterpret_cast<float4*>(&vl[0][0] + (size_t)idx * 4) =
            *reinterpret_cast<const float4*>(src + (size_t)idx * 4);
    }
    __syncthreads();
    const int c1 = c1g * 16 + (t >> 4);
    const int c2b = (t & 15) * 4;
    float m2[4] = {0,0,0,0}, m21[4] = {0,0,0,0}, m22[4] = {0,0,0,0};
    for (int i = 0; i < 32; i++) {
        float x1 = vl[i][c1];
        #pragma unroll
        for (int q = 0; q < 4; q++) {
            float x2 = vl[i][c2b + q];
            float tt = x1 * x2;
            m2[q]  += tt;
            m21[q] += x1 * tt;        // x1^2 * x2
            m22[q] += tt * tt;        // x1^2 * x2^2
        }
    }
    const int pl = (t >> 4) * 64 + c2b;
    float* base = mom + (size_t)bid * 3072;
    *reinterpret_cast<float4*>(base + pl)        = *reinterpret_cast<float4*>(m2);
    *reinterpret_cast<float4*>(base + 1024 + pl) = *reinterpret_cast<float4*>(m21);
    *reinterpret_cast<float4*>(base + 2048 + pl) = *reinterpret_cast<float4*>(m22);
    if (c1g == 0 && t < 64) {
        float s1 = 0.f, s2 = 0.f;
        for (int i = 0; i < 32; i++) { float x = vl[i][t]; s1 += x; s2 += x * x; }
        s1p[(size_t)(b * 5 + ic) * 64 + t] = s1;
        s2p[(size_t)(b * 5 + ic) * 64 + t] = s2;
    }
}

// S[c1,c2] = sum_b sum_{i,j} (v_ic1-v_jc1)^2 (v_ic2-v_jc2)^2   (+ T1 for means)
// grid 256 blocks; thread = (pi_local 16, b 16); LDS-reduce over b.
__global__ __launch_bounds__(256)
void k_S(const float* __restrict__ mom, const float* __restrict__ s1p,
         const float* __restrict__ s2p, float* __restrict__ Ssum,
         float* __restrict__ T1) {
    __shared__ float red[256];
    const int t = threadIdx.x;
    const int pl = t >> 4, b = t & 15;
    const int pi = blockIdx.x * 16 + pl;       // 0..4095
    const int c1 = pi >> 6, c2 = pi & 63;
    const int bidA = (b * 4 + (c1 >> 4)) * 5;
    const int plA  = (c1 & 15) * 64 + c2;
    const int bidB = (b * 4 + (c2 >> 4)) * 5;
    const int plB  = (c2 & 15) * 64 + c1;
    float m2 = 0.f, m21 = 0.f, m22 = 0.f, m21T = 0.f;
    float s1c1 = 0.f, s1c2 = 0.f, s2c1 = 0.f, s2c2 = 0.f;
    #pragma unroll
    for (int ic = 0; ic < 5; ic++) {
        const float* base = mom + (size_t)(bidA + ic) * 3072;
        m2   += base[plA];
        m21  += base[1024 + plA];
        m22  += base[2048 + plA];
        m21T += mom[(size_t)(bidB + ic) * 3072 + 1024 + plB];
        s1c1 += s1p[(size_t)(b * 5 + ic) * 64 + c1];
        s1c2 += s1p[(size_t)(b * 5 + ic) * 64 + c2];
        s2c1 += s2p[(size_t)(b * 5 + ic) * 64 + c1];
        s2c2 += s2p[(size_t)(b * 5 + ic) * 64 + c2];
    }
    float S = 2.f*(float)N_*m22 + 2.f*s2c1*s2c2 + 4.f*m2*m2
            - 4.f*m21*s1c2 - 4.f*m21T*s1c1;
    red[t] = S; __syncthreads();
    #pragma unroll
    for (int off = 8; off; off >>= 1) {
        if (b < off) red[t] += red[t + off];
        __syncthreads();
    }
    if (b == 0) Ssum[pi] = red[t];
    if (blockIdx.x < 4) {                      // pi < 64: T1[pi], index c = c2 = pi
        float tv = 2.f*(float)N_*s2c2 - 2.f*s1c2*s1c2;
        __syncthreads();
        red[t] = tv; __syncthreads();
        #pragma unroll
        for (int off = 8; off; off >>= 1) {
            if (b < off) red[t] += red[t + off];
            __syncthreads();
        }
        if (b == 0) T1[pi] = red[t];
    }
}

// per-o BN1 constants: cA = g*rsqrt(var+eps), cB = b - mean*cA
__global__ __launch_bounds__(64)
void k_bn1const(const float* __restrict__ Ssum, const float* __restrict__ T1,
                const float* __restrict__ w1, const float* __restrict__ g1,
                const float* __restrict__ b1, float* __restrict__ c1c) {
    const int o = blockIdx.x;      // 0..127
    const int c1 = threadIdx.x;    // 0..63
    const float* wrow = w1 + (size_t)o * 64;
    float wc1 = wrow[c1];
    float acc = 0.f;
    for (int c2 = 0; c2 < 64; c2++)
        acc += wrow[c2] * Ssum[c1 * 64 + c2];
    float qf = wc1 * acc;
    float mn = wc1 * T1[c1];
    #pragma unroll
    for (int off = 32; off; off >>= 1) {
        qf += __shfl_xor(qf, off, 64);
        mn += __shfl_xor(mn, off, 64);
    }
    if (c1 == 0) {
        const float inv = 1.f / (float)BNN;
        float mean = mn * inv;
        float var  = qf * inv - mean * mean;
        float a = g1[o] * rsqrtf(var + 1e-5f);
        c1c[o] = a;
        c1c[128 + o] = b1[o] - mean * a;
    }
}

// ---------------- fused: sim -> GEMM1 -> BN1+lrelu -> GEMM2 -> z2 + stats2 ---
// One block per (b,i) row; loops all 5 j-tiles. 3 barriers/iter.
__global__ __launch_bounds__(256, 4)
void k_fused(const float* __restrict__ v, const u16* __restrict__ w1b,
             const float* __restrict__ c1c, const u16* __restrict__ w2b,
             u16* __restrict__ z2b, float* __restrict__ partials) {
    __shared__ __align__(16) u16 simT[32 * 64];
    __shared__ __align__(16) u16 h1T[32 * 128];
    __shared__ __align__(16) u16 z2T[32 * 64];
    __shared__ float sb_s[4][64];
    __shared__ float sb_ss[4][64];
    const int ri = blockIdx.x;       // b*N + i
    const int t = threadIdx.x;
    const int bb = ri / N_;
    const int w = t >> 6, lane = t & 63;
    const int l15 = lane & 15, kgrp = lane >> 4, k0 = kgrp * 8;
    const int jt16 = w & 1;          // GEMM1 row-half  (== q)
    const int rh = w >> 1, q = w & 1; // GEMM2 row-half / col-half
    const int obase = rh * 64;       // GEMM1 o-quadrant

    // ---- hoisted per-block state ----
    const int jj = t >> 3, c0 = (t & 7) * 8;
    const float* __restrict__ vi = v + (size_t)ri * C_;
    const float* __restrict__ vrow = v + (size_t)bb * N_ * C_;
    float fi[8] __attribute__((aligned(16)));
    *reinterpret_cast<float4*>(&fi[0]) = *reinterpret_cast<const float4*>(vi + c0);
    *reinterpret_cast<float4*>(&fi[4]) = *reinterpret_cast<const float4*>(vi + c0 + 4);

    frag_ab bfrag[4][2];
    float cAr[4], cBr[4];
    #pragma unroll
    for (int tt = 0; tt < 4; tt++) {
        int o = obase + tt * 16 + l15;
        #pragma unroll
        for (int kk = 0; kk < 2; kk++)
            bfrag[tt][kk] = *reinterpret_cast<const frag_ab*>(w1b + o * 64 + kk * 32 + k0);
        cAr[tt] = c1c[o];
        cBr[tt] = c1c[128 + o];
    }

    float s_l[2] = {0.f, 0.f}, ss_l[2] = {0.f, 0.f};
    float fj[8] __attribute__((aligned(16)));
    {
        const float* vj = vrow + (size_t)jj * C_ + c0;
        *reinterpret_cast<float4*>(&fj[0]) = *reinterpret_cast<const float4*>(vj);
        *reinterpret_cast<float4*>(&fj[4]) = *reinterpret_cast<const float4*>(vj + 4);
    }

    for (int jt = 0; jt < 5; jt++) {
        // ---- P1: coalesced store of previous z2 tile + build sim tile ----
        if (jt > 0) {
            const size_t rowb = (size_t)ri * N_ + (size_t)(jt - 1) * 32;
            int idx = (jj * 64 + c0) ^ ((jj & 7) << 3);
            frag_ab zz = *reinterpret_cast<const frag_ab*>(&z2T[idx]);
            *reinterpret_cast<frag_ab*>(z2b + (rowb + jj) * C_ + c0) = zz;
        }
        {
            frag_ab pack;
            #pragma unroll
            for (int p8 = 0; p8 < 8; p8++) {
                float d = fi[p8] - fj[p8];
                pack[p8] = (short)f2bf(d * d);
            }
            int idx = (jj * 64 + c0) ^ ((jj & 7) << 3);
            *reinterpret_cast<frag_ab*>(&simT[idx]) = pack;
        }
        __syncthreads();                                   // bar1

        // ---- P2: GEMM1 + BN1/lrelu pack -> h1T ----
        frag_cd acc1[4];
        #pragma unroll
        for (int tt = 0; tt < 4; tt++) acc1[tt] = frag_cd{0.f, 0.f, 0.f, 0.f};
        #pragma unroll
        for (int kk = 0; kk < 2; kk++) {
            const int rj = jt16 * 16 + l15;
            const int idx = (rj * 64 + kk * 32 + k0) ^ ((rj & 7) << 3);
            frag_ab a = *reinterpret_cast<const frag_ab*>(&simT[idx]);
            #pragma unroll
            for (int tt = 0; tt < 4; tt++)
                acc1[tt] = __builtin_amdgcn_mfma_f32_16x16x32_bf16(a, bfrag[tt][kk], acc1[tt], 0, 0, 0);
        }
        #pragma unroll
        for (int tt = 0; tt < 4; tt++) {
            const int o = obase + tt * 16 + l15;
            #pragma unroll
            for (int r = 0; r < 4; r++) {
                const int row = jt16 * 16 + kgrp * 4 + r;
                float hv = lrelu(acc1[tt][r] * cAr[tt] + cBr[tt]);
                h1T[(row * 128 + o) ^ ((row & 7) << 3)] = f2bf(hv);
            }
        }
        __syncthreads();                                   // bar2

        // ---- P3: prefetch next fj, GEMM2, pack z2T, stats ----
        if (jt < 4) {
            const float* vj = vrow + ((size_t)(jt + 1) * 32 + jj) * C_ + c0;
            *reinterpret_cast<float4*>(&fj[0]) = *reinterpret_cast<const float4*>(vj);
            *reinterpret_cast<float4*>(&fj[4]) = *reinterpret_cast<const float4*>(vj + 4);
        }
        frag_cd acc2[2];
        acc2[0] = frag_cd{0.f,0.f,0.f,0.f}; acc2[1] = frag_cd{0.f,0.f,0.f,0.f};
        #pragma unroll
        for (int kk = 0; kk < 4; kk++) {
            const int rr = rh * 16 + l15;
            const int idx = (rr * 128 + kk * 32 + k0) ^ ((rr & 7) << 3);
            frag_ab a = *reinterpret_cast<const frag_ab*>(&h1T[idx]);
            #pragma unroll
            for (int tt = 0; tt < 2; tt++) {
                const int p = q * 32 + tt * 16 + l15;
                frag_ab bfr = *reinterpret_cast<const frag_ab*>(w2b + (size_t)p * 128 + kk * 32 + k0);
                acc2[tt] = __builtin_amdgcn_mfma_f32_16x16x32_bf16(a, bfr, acc2[tt], 0, 0, 0);
            }
        }
        #pragma unroll
        for (int tt = 0; tt < 2; tt++) {
            const int p = q * 32 + tt * 16 + l15;
            #pragma unroll
            for (int r = 0; r < 4; r++) {
                const int row = rh * 16 + kgrp * 4 + r;
                float val = acc2[tt][r];
                z2T[(row * 64 + p) ^ ((row & 7) << 3)] = f2bf(val);
                s_l[tt] += val; ss_l[tt] += val * val;
            }
        }
        __syncthreads();                                   // bar3
    }

    // ---- epilogue: store last z2 tile ----
    {
        const size_t rowb = (size_t)ri * N_ + 4 * 32;
        int idx = (jj * 64 + c0) ^ ((jj & 7) << 3);
        frag_ab zz = *reinterpret_cast<const frag_ab*>(&z2T[idx]);
        *reinterpret_cast<frag_ab*>(z2b + (rowb + jj) * C_ + c0) = zz;
    }
    // ---- stats reduce -> transposed partials [c][block] ----
    #pragma unroll
    for (int tt = 0; tt < 2; tt++) {
        s_l[tt]  += __shfl_xor(s_l[tt], 16, 64);  s_l[tt]  += __shfl_xor(s_l[tt], 32, 64);
        ss_l[tt] += __shfl_xor(ss_l[tt], 16, 64); ss_l[tt] += __shfl_xor(ss_l[tt], 32, 64);
    }
    if (lane < 16) {
        #pragma unroll
        for (int tt = 0; tt < 2; tt++) {
            const int p = q * 32 + tt * 16 + l15;
            sb_s[w][p]  = s_l[tt];
            sb_ss[w][p] = ss_l[tt];
        }
    }
    __syncthreads();
    if (t < 64) {
        const int qq = t >> 5;
        partials[(size_t)t * ROWS_BN + ri]        = sb_s[qq][t]  + sb_s[qq + 2][t];
        partials[(size_t)(64 + t) * ROWS_BN + ri] = sb_ss[qq][t] + sb_ss[qq + 2][t];
    }
}

// transposed-layout stats reduction: block c sums partials[c][0..nb)
__global__ __launch_bounds__(256)
void k_reduce_statsT(const float* __restrict__ partials, float* __restrict__ stats) {
    const int c = blockIdx.x;
    const int t = threadIdx.x;
    float s = 0.f;
    for (int b = t; b < ROWS_BN; b += 256) s += partials[(size_t)c * ROWS_BN + b];
    __shared__ float ls[256];
    ls[t] = s; __syncthreads();
    for (int off = 128; off; off >>= 1) { if (t < off) ls[t] += ls[t + off]; __syncthreads(); }
    if (t == 0) stats[c] = ls[0];
}

__global__ __launch_bounds__(64)
void k_bn2const(const float* __restrict__ stats2, const float* __restrict__ g2,
                const float* __restrict__ b2, float* __restrict__ c2c) {
    const int c = threadIdx.x;  // 0..63
    const float inv = 1.f / (float)BNN;
    float mean = stats2[c] * inv;
    float var  = stats2[64 + c] * inv - mean * mean;
    float a = g2[c] * rsqrtf(var + 1e-5f);
    c2c[c] = a; c2c[64 + c] = b2[c] - mean * a;
}

// ---------------- e = sigmoid( sum_p lrelu(bn2(z2)) * w3 + b3 ) --------------
__global__ __launch_bounds__(256)
void k_escore(const u16* __restrict__ z2b, const float* __restrict__ c2c,
              const float* __restrict__ w3, const float* __restrict__ b3,
              float* __restrict__ e_out) {
    __shared__ float cs[192];
    const int t = threadIdx.x;
    if (t < 128) cs[t] = c2c[t];
    else if (t < 192) cs[t] = w3[t - 128];
    __syncthreads();
    const size_t row = (size_t)blockIdx.x * 32 + (t >> 3);
    const int c0 = (t & 7) * 8;
    frag_ab z = *reinterpret_cast<const frag_ab*>(z2b + row * C_ + c0);
    float acc = 0.f;
    #pragma unroll
    for (int qi = 0; qi < 8; qi++) {
        const int c = c0 + qi;
        float f = bf2f((u16)z[qi]);
        acc += lrelu(f * cs[c] + cs[64 + c]) * cs[128 + c];
    }
    acc += __shfl_xor(acc, 1, 64); acc += __shfl_xor(acc, 2, 64); acc += __shfl_xor(acc, 4, 64);
    if ((t & 7) == 0) e_out[row] = 1.f / (1.f + __expf(-(acc + b3[0])));
}

// ---------------- edge renormalization chain --------------------------------
__device__ __forceinline__ float block_sum(float v, float* lds) {
    #pragma unroll
    for (int off = 32; off; off >>= 1) v += __shfl_xor(v, off, 64);
    __syncthreads();
    if ((threadIdx.x & 63) == 0) lds[threadIdx.x >> 6] = v;
    __syncthreads();
    return lds[0] + lds[1] + lds[2] + lds[3];
}

__global__ __launch_bounds__(256)
void k_edge(const float* __restrict__ e, const float* __restrict__ ep_in,
            float* __restrict__ pe_out) {
    __shared__ float lds[4];
    const int r = blockIdx.x;          // b*N + i
    const int t = threadIdx.x;
    const int iLoc = r % N_;
    const bool valid = t < N_;
    float epv = valid ? ep_in[(size_t)r * N_ + t] : 0.f;
    float epm = (t == iLoc) ? 0.f : epv;
    float rs = block_sum(epm, lds);
    float ev = valid ? e[(size_t)r * N_ + t] : 0.f;
    float x = ev * epm;
    float s = block_sum(fabsf(x), lds);
    x = x / fmaxf(s, 1e-12f) * rs;
    x += ((t == iLoc) ? 1.f : 0.f) + 1e-6f;
    float tot = block_sum(valid ? x : 0.f, lds);
    if (valid) pe_out[(size_t)r * N_ + t] = x / tot;
}

// ---------------- P2DAgg ----------------------------------------------------
__global__ __launch_bounds__(256)
void k_p2d(const float* __restrict__ pe, const float* __restrict__ dn_in,
           const float* __restrict__ W, const float* __restrict__ bias,
           float* __restrict__ dn_out) {
    __shared__ float xl[2 * S_];
    const int r = blockIdx.x;
    const int t = threadIdx.x;
    if (t < S_)            xl[t] = pe[(size_t)r * N_ + t];
    else if (t < 2 * S_)   xl[t] = dn_in[(size_t)r * S_ + (t - S_)];
    __syncthreads();
    if (t < S_) {
        float acc = bias[t];
        const float* wr = W + (size_t)t * (2 * S_);
        #pragma unroll 4
        for (int k = 0; k < 2 * S_; k++) acc += xl[k] * wr[k];
        dn_out[(size_t)r * S_ + t] = lrelu(acc);
    }
}

// ---------------- launch -----------------------------------------------------
extern "C" void kernel_launch(void* const* d_in, const int* in_sizes, int n_in,
                              void* d_out, int out_size, void* d_ws, size_t ws_size,
                              hipStream_t stream) {
    const float* middle = (const float*)d_in[0];
    const float* point  = (const float*)d_in[1];
    const float* dnode  = (const float*)d_in[2];
    // d_in[3] = distribution_edge: unused by the reference forward
    const float* pedge  = (const float*)d_in[4];
    const float* w1 = (const float*)d_in[5];
    const float* g1 = (const float*)d_in[6];
    const float* b1 = (const float*)d_in[7];
    const float* w2 = (const float*)d_in[8];
    const float* g2 = (const float*)d_in[9];
    const float* b2 = (const float*)d_in[10];
    const float* w3 = (const float*)d_in[11];
    const float* b3 = (const float*)d_in[12];
    const float* p2dw = (const float*)d_in[13];
    const float* p2db = (const float*)d_in[14];

    float* out0 = (float*)d_out;
    float* out1 = out0 + (size_t)ROWS_BN * S_;

    char* ws = (char*)d_ws;
    size_t off = 0;
    auto alloc = [&](size_t bytes) -> char* {
        char* p = ws + off;
        off += (bytes + 255) & ~(size_t)255;
        return p;
    };
    u16*   z2b      = (u16*)  alloc((size_t)BNN * C_ * 2);      // 52.4 MB
    u16*   w1b      = (u16*)  alloc(TWO_C * C_ * 2);
    u16*   w2b      = (u16*)  alloc(C_ * TWO_C * 2);
    float* e_buf    = (float*)alloc((size_t)BNN * 4);
    float* pe_a     = (float*)alloc((size_t)BNN * 4);
    float* pe_b     = (float*)alloc((size_t)BNN * 4);
    float* partials = (float*)alloc((size_t)128 * ROWS_BN * 4); // 1.31 MB
    float* mom      = (float*)alloc((size_t)320 * 3072 * 4);    // 3.93 MB
    float* s1p      = (float*)alloc((size_t)16 * 5 * 64 * 4);
    float* s2p      = (float*)alloc((size_t)16 * 5 * 64 * 4);
    float* Ssum     = (float*)alloc(4096 * 4);
    float* T1       = (float*)alloc(64 * 4);
    float* c1c      = (float*)alloc(256 * 4);
    float* stats2   = (float*)alloc(128 * 4);
    float* c2c      = (float*)alloc(128 * 4);

    k_prep<<<32, 256, 0, stream>>>(w1, w2, w1b, w2b);

    // Two edge-score passes: call 0 -> middle_node, call 1 -> point_node.
    // e from point_node is reused for BOTH generations (depends only on v).
    for (int call = 0; call < 2; call++) {
        const float* v = (call == 0) ? middle : point;
        k_mom<<<320, 256, 0, stream>>>(v, mom, s1p, s2p);
        k_S<<<256, 256, 0, stream>>>(mom, s1p, s2p, Ssum, T1);
        k_bn1const<<<128, 64, 0, stream>>>(Ssum, T1, w1, g1, b1, c1c);
        k_fused<<<ROWS_BN, 256, 0, stream>>>(v, w1b, c1c, w2b, z2b, partials);
        k_reduce_statsT<<<128, 256, 0, stream>>>(partials, stats2);
        k_bn2const<<<1, 64, 0, stream>>>(stats2, g2, b2, c2c);
        k_escore<<<BNN / 32, 256, 0, stream>>>(z2b, c2c, w3, b3, e_buf);
        if (call == 0)
            k_edge<<<ROWS_BN, 256, 0, stream>>>(e_buf, pedge, pe_a);   // initial_edge
    }

    // generation 0
    k_edge<<<ROWS_BN, 256, 0, stream>>>(e_buf, pe_a, pe_b);
    k_p2d<<<ROWS_BN, 256, 0, stream>>>(pe_b, dnode, p2dw, p2db, out0);
    // generation 1
    k_edge<<<ROWS_BN, 256, 0, stream>>>(e_buf, pe_b, pe_a);
    k_p2d<<<ROWS_BN, 256, 0, stream>>>(pe_a, out0, p2dw + (size_t)S_ * 2 * S_,
                                       p2db + S_, out1);
}

// Round 4
// 271.354 us; speedup vs baseline: 2.2231x; 1.0205x over previous
//
#include <hip/hip_runtime.h>
#include <stdint.h>

#define N_ 160
#define B_ 16
#define C_ 64
#define S_ 80
#define TWO_C 128
#define BNN (B_*N_*N_)     // 409600 rows
#define ROWS_BN (B_*N_)    // 2560

typedef unsigned short u16;
using frag_ab = __attribute__((ext_vector_type(8))) short;   // 8 bf16
using frag_cd = __attribute__((ext_vector_type(4))) float;   // 4 f32

__device__ __forceinline__ u16 f2bf(float f) {
    union { float f; uint32_t u; } v; v.f = f;
    uint32_t u = v.u;
    return (u16)((u + 0x7FFFu + ((u >> 16) & 1u)) >> 16);   // RNE
}
__device__ __forceinline__ float bf2f(u16 h) {
    union { uint32_t u; float f; } v; v.u = ((uint32_t)h) << 16;
    return v.f;
}
__device__ __forceinline__ float lrelu(float x) { return x >= 0.f ? x : 0.01f * x; }

// ---------------- weight prep: f32 -> bf16 ----------------
__global__ void k_prep(const float* __restrict__ w1, const float* __restrict__ w2,
                       u16* __restrict__ w1b, u16* __restrict__ w2b) {
    int i = blockIdx.x * 256 + threadIdx.x;
    if (i < TWO_C * C_) { w1b[i] = f2bf(w1[i]); w2b[i] = f2bf(w2[i]); }
}

// ---------------- closed-form BN1 stats: moments of v ------------------------
__global__ __launch_bounds__(256)
void k_mom(const float* __restrict__ v, float* __restrict__ mom,
           float* __restrict__ s1p, float* __restrict__ s2p) {
    __shared__ __align__(16) float vl[32][64];
    const int bid = blockIdx.x;
    const int ic  = bid % 5;
    const int c1g = (bid / 5) % 4;
    const int b   = bid / 20;
    const int t = threadIdx.x;
    const float* src = v + ((size_t)b * N_ + ic * 32) * C_;
    #pragma unroll
    for (int p = 0; p < 2; p++) {
        int idx = t + p * 256;                 // float4 index (512 total)
        *reinterpret_cast<float4*>(&vl[0][0] + (size_t)idx * 4) =
            *reinterpret_cast<const float4*>(src + (size_t)idx * 4);
    }
    __syncthreads();
    const int c1 = c1g * 16 + (t >> 4);
    const int c2b = (t & 15) * 4;
    float m2[4] = {0,0,0,0}, m21[4] = {0,0,0,0}, m22[4] = {0,0,0,0};
    for (int i = 0; i < 32; i++) {
        float x1 = vl[i][c1];
        #pragma unroll
        for (int q = 0; q < 4; q++) {
            float x2 = vl[i][c2b + q];
            float tt = x1 * x2;
            m2[q]  += tt;
            m21[q] += x1 * tt;        // x1^2 * x2
            m22[q] += tt * tt;        // x1^2 * x2^2
        }
    }
    const int pl = (t >> 4) * 64 + c2b;
    float* base = mom + (size_t)bid * 3072;
    *reinterpret_cast<float4*>(base + pl)        = *reinterpret_cast<float4*>(m2);
    *reinterpret_cast<float4*>(base + 1024 + pl) = *reinterpret_cast<float4*>(m21);
    *reinterpret_cast<float4*>(base + 2048 + pl) = *reinterpret_cast<float4*>(m22);
    if (c1g == 0 && t < 64) {
        float s1 = 0.f, s2 = 0.f;
        for (int i = 0; i < 32; i++) { float x = vl[i][t]; s1 += x; s2 += x * x; }
        s1p[(size_t)(b * 5 + ic) * 64 + t] = s1;
        s2p[(size_t)(b * 5 + ic) * 64 + t] = s2;
    }
}

// S[c1,c2] = sum_b sum_{i,j} (v_ic1-v_jc1)^2 (v_ic2-v_jc2)^2   (+ T1 for means)
__global__ __launch_bounds__(256)
void k_S(const float* __restrict__ mom, const float* __restrict__ s1p,
         const float* __restrict__ s2p, float* __restrict__ Ssum,
         float* __restrict__ T1) {
    __shared__ float red[256];
    const int t = threadIdx.x;
    const int pl = t >> 4, b = t & 15;
    const int pi = blockIdx.x * 16 + pl;       // 0..4095
    const int c1 = pi >> 6, c2 = pi & 63;
    const int bidA = (b * 4 + (c1 >> 4)) * 5;
    const int plA  = (c1 & 15) * 64 + c2;
    const int bidB = (b * 4 + (c2 >> 4)) * 5;
    const int plB  = (c2 & 15) * 64 + c1;
    float m2 = 0.f, m21 = 0.f, m22 = 0.f, m21T = 0.f;
    float s1c1 = 0.f, s1c2 = 0.f, s2c1 = 0.f, s2c2 = 0.f;
    #pragma unroll
    for (int ic = 0; ic < 5; ic++) {
        const float* base = mom + (size_t)(bidA + ic) * 3072;
        m2   += base[plA];
        m21  += base[1024 + plA];
        m22  += base[2048 + plA];
        m21T += mom[(size_t)(bidB + ic) * 3072 + 1024 + plB];
        s1c1 += s1p[(size_t)(b * 5 + ic) * 64 + c1];
        s1c2 += s1p[(size_t)(b * 5 + ic) * 64 + c2];
        s2c1 += s2p[(size_t)(b * 5 + ic) * 64 + c1];
        s2c2 += s2p[(size_t)(b * 5 + ic) * 64 + c2];
    }
    float S = 2.f*(float)N_*m22 + 2.f*s2c1*s2c2 + 4.f*m2*m2
            - 4.f*m21*s1c2 - 4.f*m21T*s1c1;
    red[t] = S; __syncthreads();
    #pragma unroll
    for (int off = 8; off; off >>= 1) {
        if (b < off) red[t] += red[t + off];
        __syncthreads();
    }
    if (b == 0) Ssum[pi] = red[t];
    if (blockIdx.x < 4) {                      // pi < 64: T1[pi]
        float tv = 2.f*(float)N_*s2c2 - 2.f*s1c2*s1c2;
        __syncthreads();
        red[t] = tv; __syncthreads();
        #pragma unroll
        for (int off = 8; off; off >>= 1) {
            if (b < off) red[t] += red[t + off];
            __syncthreads();
        }
        if (b == 0) T1[pi] = red[t];
    }
}

// per-o BN1 constants: cA = g*rsqrt(var+eps), cB = b - mean*cA
__global__ __launch_bounds__(64)
void k_bn1const(const float* __restrict__ Ssum, const float* __restrict__ T1,
                const float* __restrict__ w1, const float* __restrict__ g1,
                const float* __restrict__ b1, float* __restrict__ c1c) {
    const int o = blockIdx.x;      // 0..127
    const int c1 = threadIdx.x;    // 0..63
    const float* wrow = w1 + (size_t)o * 64;
    float wc1 = wrow[c1];
    float acc = 0.f;
    for (int c2 = 0; c2 < 64; c2++)
        acc += wrow[c2] * Ssum[c1 * 64 + c2];
    float qf = wc1 * acc;
    float mn = wc1 * T1[c1];
    #pragma unroll
    for (int off = 32; off; off >>= 1) {
        qf += __shfl_xor(qf, off, 64);
        mn += __shfl_xor(mn, off, 64);
    }
    if (c1 == 0) {
        const float inv = 1.f / (float)BNN;
        float mean = mn * inv;
        float var  = qf * inv - mean * mean;
        float a = g1[o] * rsqrtf(var + 1e-5f);
        c1c[o] = a;
        c1c[128 + o] = b1[o] - mean * a;
    }
}

// ---------------- fused: sim -> GEMM1 -> BN1+lrelu -> GEMM2 -> z2 + stats2 ---
// One block per (b,i) row; loops all 5 j-tiles. Partials per-block CONTIGUOUS.
__global__ __launch_bounds__(256, 4)
void k_fused(const float* __restrict__ v, const u16* __restrict__ w1b,
             const float* __restrict__ c1c, const u16* __restrict__ w2b,
             u16* __restrict__ z2b, float* __restrict__ partials) {
    __shared__ __align__(16) u16 simT[32 * 64];
    __shared__ __align__(16) u16 h1T[32 * 128];
    __shared__ __align__(16) u16 z2T[32 * 64];
    __shared__ float sb_s[4][64];
    __shared__ float sb_ss[4][64];
    const int ri = blockIdx.x;       // b*N + i
    const int t = threadIdx.x;
    const int bb = ri / N_;
    const int w = t >> 6, lane = t & 63;
    const int l15 = lane & 15, kgrp = lane >> 4, k0 = kgrp * 8;
    const int jt16 = w & 1;
    const int rh = w >> 1, q = w & 1;
    const int obase = rh * 64;

    const int jj = t >> 3, c0 = (t & 7) * 8;
    const float* __restrict__ vi = v + (size_t)ri * C_;
    const float* __restrict__ vrow = v + (size_t)bb * N_ * C_;
    float fi[8] __attribute__((aligned(16)));
    *reinterpret_cast<float4*>(&fi[0]) = *reinterpret_cast<const float4*>(vi + c0);
    *reinterpret_cast<float4*>(&fi[4]) = *reinterpret_cast<const float4*>(vi + c0 + 4);

    frag_ab bfrag[4][2];
    float cAr[4], cBr[4];
    #pragma unroll
    for (int tt = 0; tt < 4; tt++) {
        int o = obase + tt * 16 + l15;
        #pragma unroll
        for (int kk = 0; kk < 2; kk++)
            bfrag[tt][kk] = *reinterpret_cast<const frag_ab*>(w1b + o * 64 + kk * 32 + k0);
        cAr[tt] = c1c[o];
        cBr[tt] = c1c[128 + o];
    }

    float s_l[2] = {0.f, 0.f}, ss_l[2] = {0.f, 0.f};
    float fj[8] __attribute__((aligned(16)));
    {
        const float* vj = vrow + (size_t)jj * C_ + c0;
        *reinterpret_cast<float4*>(&fj[0]) = *reinterpret_cast<const float4*>(vj);
        *reinterpret_cast<float4*>(&fj[4]) = *reinterpret_cast<const float4*>(vj + 4);
    }

    for (int jt = 0; jt < 5; jt++) {
        if (jt > 0) {
            const size_t rowb = (size_t)ri * N_ + (size_t)(jt - 1) * 32;
            int idx = (jj * 64 + c0) ^ ((jj & 7) << 3);
            frag_ab zz = *reinterpret_cast<const frag_ab*>(&z2T[idx]);
            *reinterpret_cast<frag_ab*>(z2b + (rowb + jj) * C_ + c0) = zz;
        }
        {
            frag_ab pack;
            #pragma unroll
            for (int p8 = 0; p8 < 8; p8++) {
                float d = fi[p8] - fj[p8];
                pack[p8] = (short)f2bf(d * d);
            }
            int idx = (jj * 64 + c0) ^ ((jj & 7) << 3);
            *reinterpret_cast<frag_ab*>(&simT[idx]) = pack;
        }
        __syncthreads();                                   // bar1

        frag_cd acc1[4];
        #pragma unroll
        for (int tt = 0; tt < 4; tt++) acc1[tt] = frag_cd{0.f, 0.f, 0.f, 0.f};
        #pragma unroll
        for (int kk = 0; kk < 2; kk++) {
            const int rj = jt16 * 16 + l15;
            const int idx = (rj * 64 + kk * 32 + k0) ^ ((rj & 7) << 3);
            frag_ab a = *reinterpret_cast<const frag_ab*>(&simT[idx]);
            #pragma unroll
            for (int tt = 0; tt < 4; tt++)
                acc1[tt] = __builtin_amdgcn_mfma_f32_16x16x32_bf16(a, bfrag[tt][kk], acc1[tt], 0, 0, 0);
        }
        #pragma unroll
        for (int tt = 0; tt < 4; tt++) {
            const int o = obase + tt * 16 + l15;
            #pragma unroll
            for (int r = 0; r < 4; r++) {
                const int row = jt16 * 16 + kgrp * 4 + r;
                float hv = lrelu(acc1[tt][r] * cAr[tt] + cBr[tt]);
                h1T[(row * 128 + o) ^ ((row & 7) << 3)] = f2bf(hv);
            }
        }
        __syncthreads();                                   // bar2

        if (jt < 4) {
            const float* vj = vrow + ((size_t)(jt + 1) * 32 + jj) * C_ + c0;
            *reinterpret_cast<float4*>(&fj[0]) = *reinterpret_cast<const float4*>(vj);
            *reinterpret_cast<float4*>(&fj[4]) = *reinterpret_cast<const float4*>(vj + 4);
        }
        frag_cd acc2[2];
        acc2[0] = frag_cd{0.f,0.f,0.f,0.f}; acc2[1] = frag_cd{0.f,0.f,0.f,0.f};
        #pragma unroll
        for (int kk = 0; kk < 4; kk++) {
            const int rr = rh * 16 + l15;
            const int idx = (rr * 128 + kk * 32 + k0) ^ ((rr & 7) << 3);
            frag_ab a = *reinterpret_cast<const frag_ab*>(&h1T[idx]);
            #pragma unroll
            for (int tt = 0; tt < 2; tt++) {
                const int p = q * 32 + tt * 16 + l15;
                frag_ab bfr = *reinterpret_cast<const frag_ab*>(w2b + (size_t)p * 128 + kk * 32 + k0);
                acc2[tt] = __builtin_amdgcn_mfma_f32_16x16x32_bf16(a, bfr, acc2[tt], 0, 0, 0);
            }
        }
        #pragma unroll
        for (int tt = 0; tt < 2; tt++) {
            const int p = q * 32 + tt * 16 + l15;
            #pragma unroll
            for (int r = 0; r < 4; r++) {
                const int row = rh * 16 + kgrp * 4 + r;
                float val = acc2[tt][r];
                z2T[(row * 64 + p) ^ ((row & 7) << 3)] = f2bf(val);
                s_l[tt] += val; ss_l[tt] += val * val;
            }
        }
        __syncthreads();                                   // bar3
    }

    {
        const size_t rowb = (size_t)ri * N_ + 4 * 32;
        int idx = (jj * 64 + c0) ^ ((jj & 7) << 3);
        frag_ab zz = *reinterpret_cast<const frag_ab*>(&z2T[idx]);
        *reinterpret_cast<frag_ab*>(z2b + (rowb + jj) * C_ + c0) = zz;
    }
    #pragma unroll
    for (int tt = 0; tt < 2; tt++) {
        s_l[tt]  += __shfl_xor(s_l[tt], 16, 64);  s_l[tt]  += __shfl_xor(s_l[tt], 32, 64);
        ss_l[tt] += __shfl_xor(ss_l[tt], 16, 64); ss_l[tt] += __shfl_xor(ss_l[tt], 32, 64);
    }
    if (lane < 16) {
        #pragma unroll
        for (int tt = 0; tt < 2; tt++) {
            const int p = q * 32 + tt * 16 + l15;
            sb_s[w][p]  = s_l[tt];
            sb_ss[w][p] = ss_l[tt];
        }
    }
    __syncthreads();
    if (t < 64) {
        const int qq = t >> 5;
        // per-block CONTIGUOUS 512B (fully-dirty lines, no RFO / false sharing)
        partials[(size_t)ri * 128 + t]      = sb_s[qq][t]  + sb_s[qq + 2][t];
        partials[(size_t)ri * 128 + 64 + t] = sb_ss[qq][t] + sb_ss[qq + 2][t];
    }
}

// reduce partials + BN2 consts in one kernel: grid 64, block c owns channel c
__global__ __launch_bounds__(256)
void k_reduce_bn2(const float* __restrict__ partials, const float* __restrict__ g2,
                  const float* __restrict__ b2, float* __restrict__ c2c) {
    const int c = blockIdx.x;        // 0..63
    const int t = threadIdx.x;
    float s = 0.f, ss = 0.f;
    for (int b = t; b < ROWS_BN; b += 256) {
        s  += partials[(size_t)b * 128 + c];
        ss += partials[(size_t)b * 128 + 64 + c];
    }
    __shared__ float l1[256], l2[256];
    l1[t] = s; l2[t] = ss; __syncthreads();
    for (int off = 128; off; off >>= 1) {
        if (t < off) { l1[t] += l1[t + off]; l2[t] += l2[t + off]; }
        __syncthreads();
    }
    if (t == 0) {
        const float inv = 1.f / (float)BNN;
        float mean = l1[0] * inv;
        float var  = l2[0] * inv - mean * mean;
        float a = g2[c] * rsqrtf(var + 1e-5f);
        c2c[c] = a; c2c[64 + c] = b2[c] - mean * a;
    }
}

// ---------------- fused tail: escore + edge-renorm + P2DAgg, one block/row ---
// MODE 0: escore(z2)+edge            (call0: pedge -> pe_out)
// MODE 1: escore(z2)+save e+edge+p2d (call1 gen0)
// MODE 2: load e    +edge+p2d        (gen1)
__device__ __forceinline__ float block_sum(float v, float* lds) {
    #pragma unroll
    for (int off = 32; off; off >>= 1) v += __shfl_xor(v, off, 64);
    __syncthreads();
    if ((threadIdx.x & 63) == 0) lds[threadIdx.x >> 6] = v;
    __syncthreads();
    return lds[0] + lds[1] + lds[2] + lds[3];
}

template <int MODE>
__global__ __launch_bounds__(256)
void k_tail(const u16* __restrict__ z2b, const float* __restrict__ c2c,
            const float* __restrict__ w3, const float* __restrict__ b3,
            const float* __restrict__ e_in, float* __restrict__ e_out,
            const float* __restrict__ ep_in, float* __restrict__ pe_out,
            const float* __restrict__ dn_in, const float* __restrict__ W,
            const float* __restrict__ bias, float* __restrict__ dn_out) {
    __shared__ float cs[192];
    __shared__ float lds4[4];
    __shared__ float xl[2 * S_];
    const int r = blockIdx.x;          // b*N + i
    const int t = threadIdx.x;
    const bool valid = t < N_;
    float e_j = 0.f;

    if (MODE < 2) {
        if (t < 128) cs[t] = c2c[t];
        else if (t < 192) cs[t] = w3[t - 128];
        __syncthreads();
        if (valid) {
            const u16* zr = z2b + ((size_t)r * N_ + t) * C_;
            float acc = 0.f;
            #pragma unroll
            for (int cc = 0; cc < 8; cc++) {
                frag_ab z = *reinterpret_cast<const frag_ab*>(zr + cc * 8);
                #pragma unroll
                for (int qi = 0; qi < 8; qi++) {
                    const int c = cc * 8 + qi;
                    float f = bf2f((u16)z[qi]);
                    acc += lrelu(f * cs[c] + cs[64 + c]) * cs[128 + c];
                }
            }
            e_j = 1.f / (1.f + __expf(-(acc + b3[0])));
            if (MODE == 1) e_out[(size_t)r * N_ + t] = e_j;
        }
    } else {
        if (valid) e_j = e_in[(size_t)r * N_ + t];
    }

    // ---- edge renormalization (row-local) ----
    const int iLoc = r % N_;
    float epv = valid ? ep_in[(size_t)r * N_ + t] : 0.f;
    float epm = (t == iLoc) ? 0.f : epv;
    float rs = block_sum(epm, lds4);
    float x = e_j * epm;
    float s = block_sum(fabsf(x), lds4);
    x = x / fmaxf(s, 1e-12f) * rs;
    x += ((t == iLoc) ? 1.f : 0.f) + 1e-6f;
    float tot = block_sum(valid ? x : 0.f, lds4);
    float pv = x / tot;
    if (valid) pe_out[(size_t)r * N_ + t] = pv;

    if (MODE >= 1) {
        if (t < S_)            xl[t] = pv;                           // pe[:, :S]
        if (t < S_)            xl[S_ + t] = dn_in[(size_t)r * S_ + t];
        __syncthreads();
        if (t < S_) {
            float acc = bias[t];
            const float* wr = W + (size_t)t * (2 * S_);
            #pragma unroll 4
            for (int k = 0; k < 2 * S_; k++) acc += xl[k] * wr[k];
            dn_out[(size_t)r * S_ + t] = lrelu(acc);
        }
    }
}

// ---------------- launch -----------------------------------------------------
extern "C" void kernel_launch(void* const* d_in, const int* in_sizes, int n_in,
                              void* d_out, int out_size, void* d_ws, size_t ws_size,
                              hipStream_t stream) {
    const float* middle = (const float*)d_in[0];
    const float* point  = (const float*)d_in[1];
    const float* dnode  = (const float*)d_in[2];
    // d_in[3] = distribution_edge: unused by the reference forward
    const float* pedge  = (const float*)d_in[4];
    const float* w1 = (const float*)d_in[5];
    const float* g1 = (const float*)d_in[6];
    const float* b1 = (const float*)d_in[7];
    const float* w2 = (const float*)d_in[8];
    const float* g2 = (const float*)d_in[9];
    const float* b2 = (const float*)d_in[10];
    const float* w3 = (const float*)d_in[11];
    const float* b3 = (const float*)d_in[12];
    const float* p2dw = (const float*)d_in[13];
    const float* p2db = (const float*)d_in[14];

    float* out0 = (float*)d_out;
    float* out1 = out0 + (size_t)ROWS_BN * S_;

    char* ws = (char*)d_ws;
    size_t off = 0;
    auto alloc = [&](size_t bytes) -> char* {
        char* p = ws + off;
        off += (bytes + 255) & ~(size_t)255;
        return p;
    };
    u16*   z2b      = (u16*)  alloc((size_t)BNN * C_ * 2);      // 52.4 MB
    u16*   w1b      = (u16*)  alloc(TWO_C * C_ * 2);
    u16*   w2b      = (u16*)  alloc(C_ * TWO_C * 2);
    float* e_buf    = (float*)alloc((size_t)BNN * 4);
    float* pe_a     = (float*)alloc((size_t)BNN * 4);
    float* pe_b     = (float*)alloc((size_t)BNN * 4);
    float* partials = (float*)alloc((size_t)ROWS_BN * 128 * 4); // 1.31 MB
    float* mom      = (float*)alloc((size_t)320 * 3072 * 4);    // 3.93 MB
    float* s1p      = (float*)alloc((size_t)16 * 5 * 64 * 4);
    float* s2p      = (float*)alloc((size_t)16 * 5 * 64 * 4);
    float* Ssum     = (float*)alloc(4096 * 4);
    float* T1       = (float*)alloc(64 * 4);
    float* c1c      = (float*)alloc(256 * 4);
    float* c2c      = (float*)alloc(128 * 4);

    k_prep<<<32, 256, 0, stream>>>(w1, w2, w1b, w2b);

    // call 0 = middle_node, call 1 = point_node.
    // e(point_node) reused for BOTH generations (depends only on v).
    for (int call = 0; call < 2; call++) {
        const float* v = (call == 0) ? middle : point;
        k_mom<<<320, 256, 0, stream>>>(v, mom, s1p, s2p);
        k_S<<<256, 256, 0, stream>>>(mom, s1p, s2p, Ssum, T1);
        k_bn1const<<<128, 64, 0, stream>>>(Ssum, T1, w1, g1, b1, c1c);
        k_fused<<<ROWS_BN, 256, 0, stream>>>(v, w1b, c1c, w2b, z2b, partials);
        k_reduce_bn2<<<64, 256, 0, stream>>>(partials, g2, b2, c2c);
        if (call == 0) {
            // escore(middle) + initial edge: pedge -> pe_a
            k_tail<0><<<ROWS_BN, 256, 0, stream>>>(z2b, c2c, w3, b3,
                nullptr, nullptr, pedge, pe_a, nullptr, nullptr, nullptr, nullptr);
        } else {
            // escore(point) + save e + gen0 edge (pe_a -> pe_b) + p2d gen0
            k_tail<1><<<ROWS_BN, 256, 0, stream>>>(z2b, c2c, w3, b3,
                nullptr, e_buf, pe_a, pe_b, dnode, p2dw, p2db, out0);
        }
    }
    // gen1: load e + edge (pe_b -> pe_a) + p2d gen1
    k_tail<2><<<ROWS_BN, 256, 0, stream>>>(nullptr, nullptr, nullptr, nullptr,
        e_buf, nullptr, pe_b, pe_a, out0, p2dw + (size_t)S_ * 2 * S_, p2db + S_, out1);
}

// Round 5
// 211.061 us; speedup vs baseline: 2.8581x; 1.2857x over previous
//
#include <hip/hip_runtime.h>
#include <stdint.h>

#define N_ 160
#define B_ 16
#define C_ 64
#define S_ 80
#define TWO_C 128
#define BNN (B_*N_*N_)     // 409600 rows
#define ROWS_BN (B_*N_)    // 2560

typedef unsigned short u16;
using frag_ab = __attribute__((ext_vector_type(8))) short;   // 8 bf16
using frag_cd = __attribute__((ext_vector_type(4))) float;   // 4 f32

__device__ __forceinline__ u16 f2bf(float f) {
    union { float f; uint32_t u; } v; v.f = f;
    uint32_t u = v.u;
    return (u16)((u + 0x7FFFu + ((u >> 16) & 1u)) >> 16);   // RNE
}
__device__ __forceinline__ float bf2f(u16 h) {
    union { uint32_t u; float f; } v; v.u = ((uint32_t)h) << 16;
    return v.f;
}
__device__ __forceinline__ float lrelu(float x) { return x >= 0.f ? x : 0.01f * x; }

// ---------------- weight prep: f32 -> bf16 ----------------
__global__ void k_prep(const float* __restrict__ w1, const float* __restrict__ w2,
                       u16* __restrict__ w1b, u16* __restrict__ w2b) {
    int i = blockIdx.x * 256 + threadIdx.x;
    if (i < TWO_C * C_) { w1b[i] = f2bf(w1[i]); w2b[i] = f2bf(w2[i]); }
}

// ---------------- closed-form BN1 stats: moments of v (BOTH calls) -----------
// grid 640 = call(2) x b(16) x c1g(4) x ichunk(5)
__global__ __launch_bounds__(256)
void k_mom(const float* __restrict__ v0, const float* __restrict__ v1,
           float* __restrict__ mom, float* __restrict__ s1p, float* __restrict__ s2p) {
    __shared__ __align__(16) float vl[32][64];
    const int gbid = blockIdx.x;
    const int call = gbid / 320;
    const int bid  = gbid % 320;
    const int ic  = bid % 5;
    const int c1g = (bid / 5) % 4;
    const int b   = bid / 20;
    const int t = threadIdx.x;
    const float* v = call ? v1 : v0;
    const float* src = v + ((size_t)b * N_ + ic * 32) * C_;
    #pragma unroll
    for (int p = 0; p < 2; p++) {
        int idx = t + p * 256;
        *reinterpret_cast<float4*>(&vl[0][0] + (size_t)idx * 4) =
            *reinterpret_cast<const float4*>(src + (size_t)idx * 4);
    }
    __syncthreads();
    const int c1 = c1g * 16 + (t >> 4);
    const int c2b = (t & 15) * 4;
    float m2[4] = {0,0,0,0}, m21[4] = {0,0,0,0}, m22[4] = {0,0,0,0};
    for (int i = 0; i < 32; i++) {
        float x1 = vl[i][c1];
        #pragma unroll
        for (int q = 0; q < 4; q++) {
            float x2 = vl[i][c2b + q];
            float tt = x1 * x2;
            m2[q]  += tt;
            m21[q] += x1 * tt;
            m22[q] += tt * tt;
        }
    }
    const int pl = (t >> 4) * 64 + c2b;
    float* base = mom + (size_t)gbid * 3072;
    *reinterpret_cast<float4*>(base + pl)        = *reinterpret_cast<float4*>(m2);
    *reinterpret_cast<float4*>(base + 1024 + pl) = *reinterpret_cast<float4*>(m21);
    *reinterpret_cast<float4*>(base + 2048 + pl) = *reinterpret_cast<float4*>(m22);
    if (c1g == 0 && t < 64) {
        float s1 = 0.f, s2 = 0.f;
        for (int i = 0; i < 32; i++) { float x = vl[i][t]; s1 += x; s2 += x * x; }
        s1p[(size_t)(call * 80 + b * 5 + ic) * 64 + t] = s1;
        s2p[(size_t)(call * 80 + b * 5 + ic) * 64 + t] = s2;
    }
}

// S[c1,c2] + T1, both calls. grid 512 = call(2) x 256.
__global__ __launch_bounds__(256)
void k_S(const float* __restrict__ mom, const float* __restrict__ s1p,
         const float* __restrict__ s2p, float* __restrict__ Ssum,
         float* __restrict__ T1) {
    __shared__ float red[256];
    const int t = threadIdx.x;
    const int call = blockIdx.x / 256;
    const int lb = blockIdx.x % 256;
    const int pl = t >> 4, b = t & 15;
    const int pi = lb * 16 + pl;               // 0..4095
    const int c1 = pi >> 6, c2 = pi & 63;
    const float* momc = mom + (size_t)call * 320 * 3072;
    const float* s1c = s1p + (size_t)call * 80 * 64;
    const float* s2c = s2p + (size_t)call * 80 * 64;
    const int bidA = (b * 4 + (c1 >> 4)) * 5;
    const int plA  = (c1 & 15) * 64 + c2;
    const int bidB = (b * 4 + (c2 >> 4)) * 5;
    const int plB  = (c2 & 15) * 64 + c1;
    float m2 = 0.f, m21 = 0.f, m22 = 0.f, m21T = 0.f;
    float s1c1 = 0.f, s1c2 = 0.f, s2c1 = 0.f, s2c2 = 0.f;
    #pragma unroll
    for (int ic = 0; ic < 5; ic++) {
        const float* base = momc + (size_t)(bidA + ic) * 3072;
        m2   += base[plA];
        m21  += base[1024 + plA];
        m22  += base[2048 + plA];
        m21T += momc[(size_t)(bidB + ic) * 3072 + 1024 + plB];
        s1c1 += s1c[(size_t)(b * 5 + ic) * 64 + c1];
        s1c2 += s1c[(size_t)(b * 5 + ic) * 64 + c2];
        s2c1 += s2c[(size_t)(b * 5 + ic) * 64 + c1];
        s2c2 += s2c[(size_t)(b * 5 + ic) * 64 + c2];
    }
    float S = 2.f*(float)N_*m22 + 2.f*s2c1*s2c2 + 4.f*m2*m2
            - 4.f*m21*s1c2 - 4.f*m21T*s1c1;
    red[t] = S; __syncthreads();
    #pragma unroll
    for (int off = 8; off; off >>= 1) {
        if (b < off) red[t] += red[t + off];
        __syncthreads();
    }
    if (b == 0) Ssum[call * 4096 + pi] = red[t];
    if (lb < 4) {                              // pi < 64: T1
        float tv = 2.f*(float)N_*s2c2 - 2.f*s1c2*s1c2;
        __syncthreads();
        red[t] = tv; __syncthreads();
        #pragma unroll
        for (int off = 8; off; off >>= 1) {
            if (b < off) red[t] += red[t + off];
            __syncthreads();
        }
        if (b == 0) T1[call * 64 + pi] = red[t];
    }
}

// per-o BN1 constants, both calls. grid 256 = call(2) x o(128).
__global__ __launch_bounds__(64)
void k_bn1const(const float* __restrict__ Ssum, const float* __restrict__ T1,
                const float* __restrict__ w1, const float* __restrict__ g1,
                const float* __restrict__ b1, float* __restrict__ c1c) {
    const int call = blockIdx.x >> 7;
    const int o = blockIdx.x & 127;
    const int c1 = threadIdx.x;
    const float* Ss = Ssum + call * 4096;
    const float* T1c = T1 + call * 64;
    const float* wrow = w1 + (size_t)o * 64;
    float wc1 = wrow[c1];
    float acc = 0.f;
    for (int c2 = 0; c2 < 64; c2++)
        acc += wrow[c2] * Ss[c1 * 64 + c2];
    float qf = wc1 * acc;
    float mn = wc1 * T1c[c1];
    #pragma unroll
    for (int off = 32; off; off >>= 1) {
        qf += __shfl_xor(qf, off, 64);
        mn += __shfl_xor(mn, off, 64);
    }
    if (c1 == 0) {
        const float inv = 1.f / (float)BNN;
        float mean = mn * inv;
        float var  = qf * inv - mean * mean;
        float a = g1[o] * rsqrtf(var + 1e-5f);
        c1c[call * 256 + o] = a;
        c1c[call * 256 + 128 + o] = b1[o] - mean * a;
    }
}

// ---------------- fused: sim -> GEMM1 -> BN1+lrelu -> GEMM2 -> z2 + stats2 ---
// BOTH calls in one launch: grid 5120 = call(2) x row(2560). No min-waves cap.
__global__ __launch_bounds__(256)
void k_fused(const float* __restrict__ v0, const float* __restrict__ v1,
             const u16* __restrict__ w1b, const float* __restrict__ c1c_all,
             const u16* __restrict__ w2b, u16* __restrict__ z2b_all,
             float* __restrict__ partials_all) {
    __shared__ __align__(16) u16 simT[32 * 64];
    __shared__ __align__(16) u16 h1T[32 * 128];
    __shared__ __align__(16) u16 z2T[32 * 64];
    __shared__ float sb_s[4][64];
    __shared__ float sb_ss[4][64];
    const int gbid = blockIdx.x;
    const int call = gbid / ROWS_BN;
    const int ri = gbid % ROWS_BN;   // b*N + i
    const float* __restrict__ v = call ? v1 : v0;
    const float* __restrict__ c1c = c1c_all + call * 256;
    u16* __restrict__ z2b = z2b_all + (size_t)call * BNN * C_;
    float* __restrict__ partials = partials_all + (size_t)call * ROWS_BN * 128;

    const int t = threadIdx.x;
    const int bb = ri / N_;
    const int w = t >> 6, lane = t & 63;
    const int l15 = lane & 15, kgrp = lane >> 4, k0 = kgrp * 8;
    const int jt16 = w & 1;
    const int rh = w >> 1, q = w & 1;
    const int obase = rh * 64;

    const int jj = t >> 3, c0 = (t & 7) * 8;
    const float* __restrict__ vi = v + (size_t)ri * C_;
    const float* __restrict__ vrow = v + (size_t)bb * N_ * C_;
    float fi[8] __attribute__((aligned(16)));
    *reinterpret_cast<float4*>(&fi[0]) = *reinterpret_cast<const float4*>(vi + c0);
    *reinterpret_cast<float4*>(&fi[4]) = *reinterpret_cast<const float4*>(vi + c0 + 4);

    frag_ab bfrag[4][2];
    float cAr[4], cBr[4];
    #pragma unroll
    for (int tt = 0; tt < 4; tt++) {
        int o = obase + tt * 16 + l15;
        #pragma unroll
        for (int kk = 0; kk < 2; kk++)
            bfrag[tt][kk] = *reinterpret_cast<const frag_ab*>(w1b + o * 64 + kk * 32 + k0);
        cAr[tt] = c1c[o];
        cBr[tt] = c1c[128 + o];
    }

    float s_l[2] = {0.f, 0.f}, ss_l[2] = {0.f, 0.f};
    float fj[8] __attribute__((aligned(16)));
    {
        const float* vj = vrow + (size_t)jj * C_ + c0;
        *reinterpret_cast<float4*>(&fj[0]) = *reinterpret_cast<const float4*>(vj);
        *reinterpret_cast<float4*>(&fj[4]) = *reinterpret_cast<const float4*>(vj + 4);
    }

    for (int jt = 0; jt < 5; jt++) {
        if (jt > 0) {
            const size_t rowb = (size_t)ri * N_ + (size_t)(jt - 1) * 32;
            int idx = (jj * 64 + c0) ^ ((jj & 7) << 3);
            frag_ab zz = *reinterpret_cast<const frag_ab*>(&z2T[idx]);
            *reinterpret_cast<frag_ab*>(z2b + (rowb + jj) * C_ + c0) = zz;
        }
        {
            frag_ab pack;
            #pragma unroll
            for (int p8 = 0; p8 < 8; p8++) {
                float d = fi[p8] - fj[p8];
                pack[p8] = (short)f2bf(d * d);
            }
            int idx = (jj * 64 + c0) ^ ((jj & 7) << 3);
            *reinterpret_cast<frag_ab*>(&simT[idx]) = pack;
        }
        __syncthreads();                                   // bar1

        frag_cd acc1[4];
        #pragma unroll
        for (int tt = 0; tt < 4; tt++) acc1[tt] = frag_cd{0.f, 0.f, 0.f, 0.f};
        #pragma unroll
        for (int kk = 0; kk < 2; kk++) {
            const int rj = jt16 * 16 + l15;
            const int idx = (rj * 64 + kk * 32 + k0) ^ ((rj & 7) << 3);
            frag_ab a = *reinterpret_cast<const frag_ab*>(&simT[idx]);
            #pragma unroll
            for (int tt = 0; tt < 4; tt++)
                acc1[tt] = __builtin_amdgcn_mfma_f32_16x16x32_bf16(a, bfrag[tt][kk], acc1[tt], 0, 0, 0);
        }
        #pragma unroll
        for (int tt = 0; tt < 4; tt++) {
            const int o = obase + tt * 16 + l15;
            #pragma unroll
            for (int r = 0; r < 4; r++) {
                const int row = jt16 * 16 + kgrp * 4 + r;
                float hv = lrelu(acc1[tt][r] * cAr[tt] + cBr[tt]);
                h1T[(row * 128 + o) ^ ((row & 7) << 3)] = f2bf(hv);
            }
        }
        __syncthreads();                                   // bar2

        if (jt < 4) {
            const float* vj = vrow + ((size_t)(jt + 1) * 32 + jj) * C_ + c0;
            *reinterpret_cast<float4*>(&fj[0]) = *reinterpret_cast<const float4*>(vj);
            *reinterpret_cast<float4*>(&fj[4]) = *reinterpret_cast<const float4*>(vj + 4);
        }
        frag_cd acc2[2];
        acc2[0] = frag_cd{0.f,0.f,0.f,0.f}; acc2[1] = frag_cd{0.f,0.f,0.f,0.f};
        #pragma unroll
        for (int kk = 0; kk < 4; kk++) {
            const int rr = rh * 16 + l15;
            const int idx = (rr * 128 + kk * 32 + k0) ^ ((rr & 7) << 3);
            frag_ab a = *reinterpret_cast<const frag_ab*>(&h1T[idx]);
            #pragma unroll
            for (int tt = 0; tt < 2; tt++) {
                const int p = q * 32 + tt * 16 + l15;
                frag_ab bfr = *reinterpret_cast<const frag_ab*>(w2b + (size_t)p * 128 + kk * 32 + k0);
                acc2[tt] = __builtin_amdgcn_mfma_f32_16x16x32_bf16(a, bfr, acc2[tt], 0, 0, 0);
            }
        }
        #pragma unroll
        for (int tt = 0; tt < 2; tt++) {
            const int p = q * 32 + tt * 16 + l15;
            #pragma unroll
            for (int r = 0; r < 4; r++) {
                const int row = rh * 16 + kgrp * 4 + r;
                float val = acc2[tt][r];
                z2T[(row * 64 + p) ^ ((row & 7) << 3)] = f2bf(val);
                s_l[tt] += val; ss_l[tt] += val * val;
            }
        }
        __syncthreads();                                   // bar3
    }

    {
        const size_t rowb = (size_t)ri * N_ + 4 * 32;
        int idx = (jj * 64 + c0) ^ ((jj & 7) << 3);
        frag_ab zz = *reinterpret_cast<const frag_ab*>(&z2T[idx]);
        *reinterpret_cast<frag_ab*>(z2b + (rowb + jj) * C_ + c0) = zz;
    }
    #pragma unroll
    for (int tt = 0; tt < 2; tt++) {
        s_l[tt]  += __shfl_xor(s_l[tt], 16, 64);  s_l[tt]  += __shfl_xor(s_l[tt], 32, 64);
        ss_l[tt] += __shfl_xor(ss_l[tt], 16, 64); ss_l[tt] += __shfl_xor(ss_l[tt], 32, 64);
    }
    if (lane < 16) {
        #pragma unroll
        for (int tt = 0; tt < 2; tt++) {
            const int p = q * 32 + tt * 16 + l15;
            sb_s[w][p]  = s_l[tt];
            sb_ss[w][p] = ss_l[tt];
        }
    }
    __syncthreads();
    if (t < 64) {
        const int qq = t >> 5;
        partials[(size_t)ri * 128 + t]      = sb_s[qq][t]  + sb_s[qq + 2][t];
        partials[(size_t)ri * 128 + 64 + t] = sb_ss[qq][t] + sb_ss[qq + 2][t];
    }
}

// reduce partials + BN2 consts, both calls: grid 128 = call(2) x c(64)
__global__ __launch_bounds__(256)
void k_reduce_bn2(const float* __restrict__ partials_all, const float* __restrict__ g2,
                  const float* __restrict__ b2, float* __restrict__ c2c) {
    const int call = blockIdx.x >> 6;
    const int c = blockIdx.x & 63;
    const int t = threadIdx.x;
    const float* partials = partials_all + (size_t)call * ROWS_BN * 128;
    float s = 0.f, ss = 0.f;
    for (int b = t; b < ROWS_BN; b += 256) {
        s  += partials[(size_t)b * 128 + c];
        ss += partials[(size_t)b * 128 + 64 + c];
    }
    __shared__ float l1[256], l2[256];
    l1[t] = s; l2[t] = ss; __syncthreads();
    for (int off = 128; off; off >>= 1) {
        if (t < off) { l1[t] += l1[t + off]; l2[t] += l2[t + off]; }
        __syncthreads();
    }
    if (t == 0) {
        const float inv = 1.f / (float)BNN;
        float mean = l1[0] * inv;
        float var  = l2[0] * inv - mean * mean;
        float a = g2[c] * rsqrtf(var + 1e-5f);
        c2c[call * 128 + c] = a;
        c2c[call * 128 + 64 + c] = b2[c] - mean * a;
    }
}

// ---------------- fused tail: escore + edge-renorm + P2DAgg, one block/row ---
__device__ __forceinline__ float block_sum(float v, float* lds) {
    #pragma unroll
    for (int off = 32; off; off >>= 1) v += __shfl_xor(v, off, 64);
    __syncthreads();
    if ((threadIdx.x & 63) == 0) lds[threadIdx.x >> 6] = v;
    __syncthreads();
    return lds[0] + lds[1] + lds[2] + lds[3];
}

template <int MODE>
__global__ __launch_bounds__(256)
void k_tail(const u16* __restrict__ z2b, const float* __restrict__ c2c,
            const float* __restrict__ w3, const float* __restrict__ b3,
            const float* __restrict__ e_in, float* __restrict__ e_out,
            const float* __restrict__ ep_in, float* __restrict__ pe_out,
            const float* __restrict__ dn_in, const float* __restrict__ W,
            const float* __restrict__ bias, float* __restrict__ dn_out) {
    __shared__ float cs[192];
    __shared__ float lds4[4];
    __shared__ float xl[2 * S_];
    const int r = blockIdx.x;          // b*N + i
    const int t = threadIdx.x;
    const bool valid = t < N_;
    float e_j = 0.f;

    if (MODE < 2) {
        if (t < 128) cs[t] = c2c[t];
        else if (t < 192) cs[t] = w3[t - 128];
        __syncthreads();
        if (valid) {
            const u16* zr = z2b + ((size_t)r * N_ + t) * C_;
            float acc = 0.f;
            #pragma unroll
            for (int cc = 0; cc < 8; cc++) {
                frag_ab z = *reinterpret_cast<const frag_ab*>(zr + cc * 8);
                #pragma unroll
                for (int qi = 0; qi < 8; qi++) {
                    const int c = cc * 8 + qi;
                    float f = bf2f((u16)z[qi]);
                    acc += lrelu(f * cs[c] + cs[64 + c]) * cs[128 + c];
                }
            }
            e_j = 1.f / (1.f + __expf(-(acc + b3[0])));
            if (MODE == 1) e_out[(size_t)r * N_ + t] = e_j;
        }
    } else {
        if (valid) e_j = e_in[(size_t)r * N_ + t];
    }

    // ---- edge renormalization (row-local) ----
    const int iLoc = r % N_;
    float epv = valid ? ep_in[(size_t)r * N_ + t] : 0.f;
    float epm = (t == iLoc) ? 0.f : epv;
    float rs = block_sum(epm, lds4);
    float x = e_j * epm;
    float s = block_sum(fabsf(x), lds4);
    x = x / fmaxf(s, 1e-12f) * rs;
    x += ((t == iLoc) ? 1.f : 0.f) + 1e-6f;
    float tot = block_sum(valid ? x : 0.f, lds4);
    float pv = x / tot;
    if (valid) pe_out[(size_t)r * N_ + t] = pv;

    if (MODE >= 1) {
        if (t < S_)            xl[t] = pv;                           // pe[:, :S]
        if (t < S_)            xl[S_ + t] = dn_in[(size_t)r * S_ + t];
        __syncthreads();
        if (t < S_) {
            float acc = bias[t];
            const float* wr = W + (size_t)t * (2 * S_);
            #pragma unroll 4
            for (int k = 0; k < 2 * S_; k++) acc += xl[k] * wr[k];
            dn_out[(size_t)r * S_ + t] = lrelu(acc);
        }
    }
}

// ---------------- launch -----------------------------------------------------
extern "C" void kernel_launch(void* const* d_in, const int* in_sizes, int n_in,
                              void* d_out, int out_size, void* d_ws, size_t ws_size,
                              hipStream_t stream) {
    const float* middle = (const float*)d_in[0];
    const float* point  = (const float*)d_in[1];
    const float* dnode  = (const float*)d_in[2];
    // d_in[3] = distribution_edge: unused by the reference forward
    const float* pedge  = (const float*)d_in[4];
    const float* w1 = (const float*)d_in[5];
    const float* g1 = (const float*)d_in[6];
    const float* b1 = (const float*)d_in[7];
    const float* w2 = (const float*)d_in[8];
    const float* g2 = (const float*)d_in[9];
    const float* b2 = (const float*)d_in[10];
    const float* w3 = (const float*)d_in[11];
    const float* b3 = (const float*)d_in[12];
    const float* p2dw = (const float*)d_in[13];
    const float* p2db = (const float*)d_in[14];

    float* out0 = (float*)d_out;
    float* out1 = out0 + (size_t)ROWS_BN * S_;

    char* ws = (char*)d_ws;
    size_t off = 0;
    auto alloc = [&](size_t bytes) -> char* {
        char* p = ws + off;
        off += (bytes + 255) & ~(size_t)255;
        return p;
    };
    u16*   z2b      = (u16*)  alloc((size_t)2 * BNN * C_ * 2);       // 104.9 MB (both calls)
    u16*   w1b      = (u16*)  alloc(TWO_C * C_ * 2);
    u16*   w2b      = (u16*)  alloc(C_ * TWO_C * 2);
    float* e_buf    = (float*)alloc((size_t)BNN * 4);
    float* pe_a     = (float*)alloc((size_t)BNN * 4);
    float* pe_b     = (float*)alloc((size_t)BNN * 4);
    float* partials = (float*)alloc((size_t)2 * ROWS_BN * 128 * 4);  // 2.62 MB
    float* mom      = (float*)alloc((size_t)2 * 320 * 3072 * 4);     // 7.86 MB
    float* s1p      = (float*)alloc((size_t)2 * 80 * 64 * 4);
    float* s2p      = (float*)alloc((size_t)2 * 80 * 64 * 4);
    float* Ssum     = (float*)alloc(2 * 4096 * 4);
    float* T1       = (float*)alloc(2 * 64 * 4);
    float* c1c      = (float*)alloc(2 * 256 * 4);
    float* c2c      = (float*)alloc(2 * 128 * 4);

    k_prep<<<32, 256, 0, stream>>>(w1, w2, w1b, w2b);

    // Both calls (call0 = middle_node, call1 = point_node) fused per stage.
    // e(point_node) is reused for BOTH generations (depends only on v).
    k_mom<<<640, 256, 0, stream>>>(middle, point, mom, s1p, s2p);
    k_S<<<512, 256, 0, stream>>>(mom, s1p, s2p, Ssum, T1);
    k_bn1const<<<256, 64, 0, stream>>>(Ssum, T1, w1, g1, b1, c1c);
    k_fused<<<2 * ROWS_BN, 256, 0, stream>>>(middle, point, w1b, c1c, w2b, z2b, partials);
    k_reduce_bn2<<<128, 256, 0, stream>>>(partials, g2, b2, c2c);

    // escore(middle) + initial edge: pedge -> pe_a
    k_tail<0><<<ROWS_BN, 256, 0, stream>>>(z2b, c2c, w3, b3,
        nullptr, nullptr, pedge, pe_a, nullptr, nullptr, nullptr, nullptr);
    // escore(point) + save e + gen0 edge (pe_a -> pe_b) + p2d gen0
    k_tail<1><<<ROWS_BN, 256, 0, stream>>>(z2b + (size_t)BNN * C_, c2c + 128, w3, b3,
        nullptr, e_buf, pe_a, pe_b, dnode, p2dw, p2db, out0);
    // gen1: load e + edge (pe_b -> pe_a) + p2d gen1
    k_tail<2><<<ROWS_BN, 256, 0, stream>>>(nullptr, nullptr, nullptr, nullptr,
        e_buf, nullptr, pe_b, pe_a, out0, p2dw + (size_t)S_ * 2 * S_, p2db + S_, out1);
}